// Round 9
// baseline (526.285 us; speedup 1.0000x reference)
//
#include <hip/hip_runtime.h>
#include <hip/hip_bf16.h>
#include <math.h>

#define DM   512
#define HH   8
#define RR   8
#define TT   128
#define BBATCH 32
#define MM   (TT*BBATCH)     // 4096 rows
#define NPROJ 2656
#define KQV  2560

typedef __attribute__((ext_vector_type(8))) short bf16x8;
typedef __attribute__((ext_vector_type(4))) float f32x4;

__device__ __forceinline__ float sigmoidf_(float x) {
    return 1.0f / (1.0f + __expf(-x));
}

__device__ __forceinline__ void gload_lds16(const void* g, void* l) {
    __builtin_amdgcn_global_load_lds(
        (const __attribute__((address_space(1))) unsigned int*)g,
        (__attribute__((address_space(3))) unsigned int*)l, 16, 0, 0);
}

// ---- DPP wave64 sum -> uniform value --------------------------------------
template<int CTRL, int RMASK>
__device__ __forceinline__ float dpp_add_(float x) {
    union { float f; int i; } a, b;
    a.f = x;
    b.i = __builtin_amdgcn_update_dpp(0, a.i, CTRL, RMASK, 0xf, true);
    return x + b.f;
}
__device__ __forceinline__ float wave_sum_u(float x) {
    x = dpp_add_<0x111, 0xf>(x);   // row_shr:1
    x = dpp_add_<0x112, 0xf>(x);   // row_shr:2
    x = dpp_add_<0x114, 0xf>(x);   // row_shr:4
    x = dpp_add_<0x118, 0xf>(x);   // row_shr:8
    x = dpp_add_<0x142, 0xa>(x);   // row_bcast:15 -> rows 1,3
    x = dpp_add_<0x143, 0xc>(x);   // row_bcast:31 -> rows 2,3
    union { float f; int i; } s, t;
    s.f = x;
    t.i = __builtin_amdgcn_readlane(s.i, 63);
    return t.f;
}

// ---------------- merged f32->bf16 conversions + LN1 (one launch) ---------
struct F2B9 {
    const float* s[9];
    __hip_bfloat16* d[9];
    int cum[10];
};

__global__ __launch_bounds__(256) void f2b_ln_all(F2B9 a,
    const float* __restrict__ x, const float* __restrict__ g,
    const float* __restrict__ b, __hip_bfloat16* __restrict__ lnout)
{
    if (blockIdx.x < 8752) {
        int q = blockIdx.x * 256 + threadIdx.x;
        if (q >= a.cum[9]) return;
        int s = 0;
        #pragma unroll
        for (int i = 1; i < 9; ++i) s += (q >= a.cum[i]);
        int i4 = (q - a.cum[s]) * 4;
        float4 v = *(const float4*)(a.s[s] + i4);
        __hip_bfloat16* dst = a.d[s] + i4;
        dst[0] = __float2bfloat16(v.x);
        dst[1] = __float2bfloat16(v.y);
        dst[2] = __float2bfloat16(v.z);
        dst[3] = __float2bfloat16(v.w);
        return;
    }
    // ---- LayerNorm path: one row per block ----
    int row = blockIdx.x - 8752;
    int tid = threadIdx.x;
    const float* xr = x + (size_t)row * DM;
    float2 v = ((const float2*)xr)[tid];
    float s = v.x + v.y;
    #pragma unroll
    for (int off = 32; off; off >>= 1) s += __shfl_down(s, off);
    __shared__ float red[8];
    int wid = tid >> 6, lane = tid & 63;
    if (lane == 0) red[wid] = s;
    __syncthreads();
    if (tid == 0) red[0] = (red[0] + red[1] + red[2] + red[3]) * (1.0f / DM);
    __syncthreads();
    float mean = red[0];
    float dx = v.x - mean, dy = v.y - mean;
    float sq = dx*dx + dy*dy;
    #pragma unroll
    for (int off = 32; off; off >>= 1) sq += __shfl_down(sq, off);
    if (lane == 0) red[4 + wid] = sq;
    __syncthreads();
    if (tid == 0) red[1] = rsqrtf((red[4]+red[5]+red[6]+red[7]) * (1.0f/DM) + 1e-5f);
    __syncthreads();
    float rstd = red[1];
    float2 gg = ((const float2*)g)[tid];
    float2 bb = ((const float2*)b)[tid];
    __hip_bfloat16* orow = lnout + (size_t)row * DM;
    orow[2*tid+0] = __float2bfloat16(dx * rstd * gg.x + bb.x);
    orow[2*tid+1] = __float2bfloat16(dy * rstd * gg.y + bb.y);
}

// ---------------- standalone LayerNorm -> bf16 (LN2) ----------------------
__global__ __launch_bounds__(256) void ln_kernel(const float* __restrict__ x,
    const float* __restrict__ g, const float* __restrict__ b,
    __hip_bfloat16* __restrict__ out)
{
    int row = blockIdx.x;
    int tid = threadIdx.x;
    const float* xr = x + (size_t)row * DM;
    float2 v = ((const float2*)xr)[tid];
    float s = v.x + v.y;
    #pragma unroll
    for (int off = 32; off; off >>= 1) s += __shfl_down(s, off);
    __shared__ float red[8];
    int wid = tid >> 6, lane = tid & 63;
    if (lane == 0) red[wid] = s;
    __syncthreads();
    if (tid == 0) red[0] = (red[0] + red[1] + red[2] + red[3]) * (1.0f / DM);
    __syncthreads();
    float mean = red[0];
    float dx = v.x - mean, dy = v.y - mean;
    float sq = dx*dx + dy*dy;
    #pragma unroll
    for (int off = 32; off; off >>= 1) sq += __shfl_down(sq, off);
    if (lane == 0) red[4 + wid] = sq;
    __syncthreads();
    if (tid == 0) red[1] = rsqrtf((red[4]+red[5]+red[6]+red[7]) * (1.0f/DM) + 1e-5f);
    __syncthreads();
    float rstd = red[1];
    float2 gg = ((const float2*)g)[tid];
    float2 bb = ((const float2*)b)[tid];
    __hip_bfloat16* orow = out + (size_t)row * DM;
    orow[2*tid+0] = __float2bfloat16(dx * rstd * gg.x + bb.x);
    orow[2*tid+1] = __float2bfloat16(dy * rstd * gg.y + bb.y);
}

// ---------------- bf16 MFMA GEMM core: 128x128 tile, BK=32 ----------------
__device__ __forceinline__ void gemm_core128(
    const __hip_bfloat16* __restrict__ A, const __hip_bfloat16* __restrict__ W,
    const float* __restrict__ bias,
    float* __restrict__ Cf, __hip_bfloat16* __restrict__ Cb,
    int N, int K, int act, int m0, int n0)
{
    __shared__ __attribute__((aligned(16))) __hip_bfloat16 As[8*512];
    __shared__ __attribute__((aligned(16))) __hip_bfloat16 Bs[8*512];
    int tid = threadIdx.x;
    int wave = tid >> 6, lane = tid & 63;
    int wm = (wave >> 1) * 64, wn = (wave & 1) * 64;
    int fr = lane & 15, fq = lane >> 4;

    f32x4 acc[4][4];
    #pragma unroll
    for (int i = 0; i < 4; ++i)
        #pragma unroll
        for (int j = 0; j < 4; ++j)
            acc[i][j] = (f32x4){0.f, 0.f, 0.f, 0.f};

    int sm0 = wave*16 + fr;
    int sm1 = sm0 + 64;
    int wr0 = n0 + sm0; if (wr0 >= N) wr0 = N - 1;
    int wr1 = n0 + sm1; if (wr1 >= N) wr1 = N - 1;
    const __hip_bfloat16* Ag0 = A + (size_t)(m0 + sm0) * K + fq*8;
    const __hip_bfloat16* Ag1 = A + (size_t)(m0 + sm1) * K + fq*8;
    const __hip_bfloat16* Wg0 = W + (size_t)wr0 * K + fq*8;
    const __hip_bfloat16* Wg1 = W + (size_t)wr1 * K + fq*8;

    for (int k0 = 0; k0 < K; k0 += 32) {
        gload_lds16(Ag0 + k0, As + (size_t)wave*512);
        gload_lds16(Ag1 + k0, As + (size_t)(wave+4)*512);
        gload_lds16(Wg0 + k0, Bs + (size_t)wave*512);
        gload_lds16(Wg1 + k0, Bs + (size_t)(wave+4)*512);
        __syncthreads();
        bf16x8 af[4], bfr[4];
        #pragma unroll
        for (int i = 0; i < 4; ++i) {
            af[i]  = *(const bf16x8*)(As + (size_t)(wm/16 + i)*512 + lane*8);
            bfr[i] = *(const bf16x8*)(Bs + (size_t)(wn/16 + i)*512 + lane*8);
        }
        #pragma unroll
        for (int mi = 0; mi < 4; ++mi)
            #pragma unroll
            for (int ni = 0; ni < 4; ++ni)
                acc[mi][ni] = __builtin_amdgcn_mfma_f32_16x16x32_bf16(
                    af[mi], bfr[ni], acc[mi][ni], 0, 0, 0);
        __syncthreads();
    }

    #pragma unroll
    for (int ni = 0; ni < 4; ++ni) {
        int n = n0 + wn + ni*16 + fr;
        bool nok = n < N;
        float bv = (bias && nok) ? bias[n] : 0.f;
        #pragma unroll
        for (int mi = 0; mi < 4; ++mi) {
            #pragma unroll
            for (int r = 0; r < 4; ++r) {
                int m = m0 + wm + mi*16 + fq*4 + r;
                float v = acc[mi][ni][r] + bv;
                if (act) v = fmaxf(v, 0.f);
                if (nok) {
                    size_t idx = (size_t)m * N + n;
                    if (Cf) Cf[idx] = v;
                    if (Cb) Cb[idx] = __float2bfloat16(v);
                }
            }
        }
    }
}

__global__ __launch_bounds__(256) void gemm_bf16(
    const __hip_bfloat16* __restrict__ A, const __hip_bfloat16* __restrict__ W,
    const float* __restrict__ bias,
    float* __restrict__ Cf, __hip_bfloat16* __restrict__ Cb,
    int N, int K, int act)
{
    gemm_core128(A, W, bias, Cf, Cb, N, K, act, blockIdx.y * 128, blockIdx.x * 128);
}

// FFC1 + Bx2 in one launch: bx<splitX -> mid = relu(fi@fw1^T+b1) (bf16);
// else -> Bx2 = g1@[u0;u1]^T (f32). Independent work, fills occupancy.
__global__ __launch_bounds__(256) void ffc1_bx_dual(
    const __hip_bfloat16* __restrict__ Aa, const __hip_bfloat16* __restrict__ Wa,
    const float* __restrict__ biasA, __hip_bfloat16* __restrict__ CbA,
    int Na, int splitX,
    const __hip_bfloat16* __restrict__ Ab, const __hip_bfloat16* __restrict__ Wb,
    float* __restrict__ CfB, int Nb, int K)
{
    int bx = blockIdx.x;
    if (bx < splitX)
        gemm_core128(Aa, Wa, biasA, nullptr, CbA, Na, K, 1, blockIdx.y*128, bx*128);
    else
        gemm_core128(Ab, Wb, nullptr, CfB, nullptr, Nb, K, 0, blockIdx.y*128, (bx-splitX)*128);
}

// ---------------- GRU stage-1 GEMM with rz epilogue -----------------------
// A1 = y@[w0;w1;w2]^T (N=1536, K=512). Epilogue (bitwise = old gru_rz):
//   n<512:        rx  = bf16( sigmoid(v + Bx[m,n]) * x[m,n] )
//   512<=n<1024:  zb  = sigmoid(v + Bx[m,n] - 2)
//   n>=1024:      A1h = v        (tanh-preactivation, consumed by final)
__global__ __launch_bounds__(256) void gemm_gru_rz(
    const __hip_bfloat16* __restrict__ A, const __hip_bfloat16* __restrict__ W,
    const float* __restrict__ Bx, const float* __restrict__ x,
    __hip_bfloat16* __restrict__ rx, float* __restrict__ zb,
    float* __restrict__ A1h)
{
    __shared__ __attribute__((aligned(16))) __hip_bfloat16 As[8*512];
    __shared__ __attribute__((aligned(16))) __hip_bfloat16 Bs[8*512];
    const int N = 1536, K = DM;
    int tid = threadIdx.x;
    int wave = tid >> 6, lane = tid & 63;
    int m0 = blockIdx.y * 128, n0 = blockIdx.x * 128;
    int wm = (wave >> 1) * 64, wn = (wave & 1) * 64;
    int fr = lane & 15, fq = lane >> 4;

    f32x4 acc[4][4];
    #pragma unroll
    for (int i = 0; i < 4; ++i)
        #pragma unroll
        for (int j = 0; j < 4; ++j)
            acc[i][j] = (f32x4){0.f, 0.f, 0.f, 0.f};

    int sm0 = wave*16 + fr;
    int sm1 = sm0 + 64;
    const __hip_bfloat16* Ag0 = A + (size_t)(m0 + sm0) * K + fq*8;
    const __hip_bfloat16* Ag1 = A + (size_t)(m0 + sm1) * K + fq*8;
    const __hip_bfloat16* Wg0 = W + (size_t)(n0 + sm0) * K + fq*8;
    const __hip_bfloat16* Wg1 = W + (size_t)(n0 + sm1) * K + fq*8;

    for (int k0 = 0; k0 < K; k0 += 32) {
        gload_lds16(Ag0 + k0, As + (size_t)wave*512);
        gload_lds16(Ag1 + k0, As + (size_t)(wave+4)*512);
        gload_lds16(Wg0 + k0, Bs + (size_t)wave*512);
        gload_lds16(Wg1 + k0, Bs + (size_t)(wave+4)*512);
        __syncthreads();
        bf16x8 af[4], bfr[4];
        #pragma unroll
        for (int i = 0; i < 4; ++i) {
            af[i]  = *(const bf16x8*)(As + (size_t)(wm/16 + i)*512 + lane*8);
            bfr[i] = *(const bf16x8*)(Bs + (size_t)(wn/16 + i)*512 + lane*8);
        }
        #pragma unroll
        for (int mi = 0; mi < 4; ++mi)
            #pragma unroll
            for (int ni = 0; ni < 4; ++ni)
                acc[mi][ni] = __builtin_amdgcn_mfma_f32_16x16x32_bf16(
                    af[mi], bfr[ni], acc[mi][ni], 0, 0, 0);
        __syncthreads();
    }

    #pragma unroll
    for (int ni = 0; ni < 4; ++ni) {
        int n = n0 + wn + ni*16 + fr;
        #pragma unroll
        for (int mi = 0; mi < 4; ++mi) {
            #pragma unroll
            for (int r = 0; r < 4; ++r) {
                int m = m0 + wm + mi*16 + fq*4 + r;
                float v = acc[mi][ni][r];
                if (n < 512) {
                    float rpre = v + Bx[(size_t)m*1024 + n];
                    rx[(size_t)m*512 + n] =
                        __float2bfloat16(sigmoidf_(rpre) * x[(size_t)m*512 + n]);
                } else if (n < 1024) {
                    float zpre = v + Bx[(size_t)m*1024 + n] - 2.0f;
                    zb[(size_t)m*512 + (n - 512)] = sigmoidf_(zpre);
                } else {
                    A1h[(size_t)m*512 + (n - 1024)] = v;
                }
            }
        }
    }
}

// ---------------- GRU final GEMM: C2 = rx@u2^T + fused output -------------
// 64x128 tile, N=512, K=512. Epilogue (bitwise = old gru_final):
//   hh = tanh(A1h + v); o = (1-z)*x + z*hh -> outf (+ optional bf16 copy)
__global__ __launch_bounds__(256) void gemm_gru_final(
    const __hip_bfloat16* __restrict__ A, const __hip_bfloat16* __restrict__ W,
    const float* __restrict__ A1h, const float* __restrict__ zb,
    const float* __restrict__ x,
    float* __restrict__ outf, __hip_bfloat16* __restrict__ outb)
{
    __shared__ __attribute__((aligned(16))) __hip_bfloat16 As[4*512];
    __shared__ __attribute__((aligned(16))) __hip_bfloat16 Bs[8*512];
    const int K = DM;
    int tid = threadIdx.x;
    int wave = tid >> 6, lane = tid & 63;
    int m0 = blockIdx.y * 64, n0 = blockIdx.x * 128;
    int wm = (wave >> 1) * 32, wn = (wave & 1) * 64;
    int fr = lane & 15, fq = lane >> 4;

    f32x4 acc[2][4];
    #pragma unroll
    for (int i = 0; i < 2; ++i)
        #pragma unroll
        for (int j = 0; j < 4; ++j)
            acc[i][j] = (f32x4){0.f, 0.f, 0.f, 0.f};

    const __hip_bfloat16* Ag = A + (size_t)(m0 + wave*16 + fr) * K + fq*8;
    const __hip_bfloat16* Wg0 = W + (size_t)(n0 + wave*16 + fr) * K + fq*8;
    const __hip_bfloat16* Wg1 = W + (size_t)(n0 + wave*16 + fr + 64) * K + fq*8;

    for (int k0 = 0; k0 < K; k0 += 32) {
        gload_lds16(Ag  + k0, As + (size_t)wave*512);
        gload_lds16(Wg0 + k0, Bs + (size_t)wave*512);
        gload_lds16(Wg1 + k0, Bs + (size_t)(wave+4)*512);
        __syncthreads();
        bf16x8 af[2], bfr[4];
        #pragma unroll
        for (int i = 0; i < 2; ++i)
            af[i]  = *(const bf16x8*)(As + (size_t)(wm/16 + i)*512 + lane*8);
        #pragma unroll
        for (int j = 0; j < 4; ++j)
            bfr[j] = *(const bf16x8*)(Bs + (size_t)(wn/16 + j)*512 + lane*8);
        #pragma unroll
        for (int mi = 0; mi < 2; ++mi)
            #pragma unroll
            for (int ni = 0; ni < 4; ++ni)
                acc[mi][ni] = __builtin_amdgcn_mfma_f32_16x16x32_bf16(
                    af[mi], bfr[ni], acc[mi][ni], 0, 0, 0);
        __syncthreads();
    }

    #pragma unroll
    for (int ni = 0; ni < 4; ++ni) {
        int n = n0 + wn + ni*16 + fr;
        #pragma unroll
        for (int mi = 0; mi < 2; ++mi) {
            #pragma unroll
            for (int r = 0; r < 4; ++r) {
                int m = m0 + wm + mi*16 + fq*4 + r;
                size_t idx = (size_t)m * 512 + n;
                float hh = tanhf(A1h[idx] + acc[mi][ni][r]);
                float zz = zb[idx];
                float o = (1.0f - zz) * x[idx] + zz * hh;
                outf[idx] = o;
                if (outb) outb[idx] = __float2bfloat16(o);
            }
        }
    }
}

// ---------------- 64x128-tile GEMM (N=512 cases: 256 blocks) --------------
__global__ __launch_bounds__(256) void gemm_bf16_64(
    const __hip_bfloat16* __restrict__ A, const __hip_bfloat16* __restrict__ W,
    const float* __restrict__ bias,
    float* __restrict__ Cf, __hip_bfloat16* __restrict__ Cb,
    int N, int K, int act)
{
    __shared__ __attribute__((aligned(16))) __hip_bfloat16 As[4*512];
    __shared__ __attribute__((aligned(16))) __hip_bfloat16 Bs[8*512];
    int tid = threadIdx.x;
    int wave = tid >> 6, lane = tid & 63;
    int m0 = blockIdx.y * 64, n0 = blockIdx.x * 128;
    int wm = (wave >> 1) * 32, wn = (wave & 1) * 64;
    int fr = lane & 15, fq = lane >> 4;

    f32x4 acc[2][4];
    #pragma unroll
    for (int i = 0; i < 2; ++i)
        #pragma unroll
        for (int j = 0; j < 4; ++j)
            acc[i][j] = (f32x4){0.f, 0.f, 0.f, 0.f};

    const __hip_bfloat16* Ag = A + (size_t)(m0 + wave*16 + fr) * K + fq*8;
    int wr0 = n0 + wave*16 + fr; if (wr0 >= N) wr0 = N - 1;
    int wr1 = wr0 + 64;          if (wr1 >= N) wr1 = N - 1;
    const __hip_bfloat16* Wg0 = W + (size_t)wr0 * K + fq*8;
    const __hip_bfloat16* Wg1 = W + (size_t)wr1 * K + fq*8;

    for (int k0 = 0; k0 < K; k0 += 32) {
        gload_lds16(Ag  + k0, As + (size_t)wave*512);
        gload_lds16(Wg0 + k0, Bs + (size_t)wave*512);
        gload_lds16(Wg1 + k0, Bs + (size_t)(wave+4)*512);
        __syncthreads();
        bf16x8 af[2], bfr[4];
        #pragma unroll
        for (int i = 0; i < 2; ++i)
            af[i]  = *(const bf16x8*)(As + (size_t)(wm/16 + i)*512 + lane*8);
        #pragma unroll
        for (int j = 0; j < 4; ++j)
            bfr[j] = *(const bf16x8*)(Bs + (size_t)(wn/16 + j)*512 + lane*8);
        #pragma unroll
        for (int mi = 0; mi < 2; ++mi)
            #pragma unroll
            for (int ni = 0; ni < 4; ++ni)
                acc[mi][ni] = __builtin_amdgcn_mfma_f32_16x16x32_bf16(
                    af[mi], bfr[ni], acc[mi][ni], 0, 0, 0);
        __syncthreads();
    }

    #pragma unroll
    for (int ni = 0; ni < 4; ++ni) {
        int n = n0 + wn + ni*16 + fr;
        bool nok = n < N;
        float bv = (bias && nok) ? bias[n] : 0.f;
        #pragma unroll
        for (int mi = 0; mi < 2; ++mi) {
            #pragma unroll
            for (int r = 0; r < 4; ++r) {
                int m = m0 + wm + mi*16 + fq*4 + r;
                float v = acc[mi][ni][r] + bv;
                if (act) v = fmaxf(v, 0.f);
                if (nok) {
                    size_t idx = (size_t)m * N + n;
                    if (Cf) Cf[idx] = v;
                    if (Cb) Cb[idx] = __float2bfloat16(v);
                }
            }
        }
    }
}

// ---------------- fused scans + attention + co-scheduled Bx GEMM ----------
// Blocks 0..255: producer/consumer scan per (b,h). Blocks 256..511: GRU1's
// Bx = inputs@[u0;u1]^T GEMM in the scan's occupancy shadow.
// NOTE: Bx MUST NOT overlap proj (r6 race).
#define NSLOT 16
#define SLOTF 384

__global__ __launch_bounds__(256) void scan_attn_fused(
    const float* __restrict__ proj, const int* __restrict__ term,
    const float* __restrict__ tick, const float* __restrict__ tilde_k,
    const float* __restrict__ tilde_v, const float* __restrict__ s_prev,
    __hip_bfloat16* __restrict__ attn,
    const __hip_bfloat16* __restrict__ gA, const __hip_bfloat16* __restrict__ gW,
    float* __restrict__ gC)
{
    int bid = blockIdx.x;
    if (bid >= 256) {
        int g = bid - 256;
        gemm_core128(gA, gW, nullptr, gC, nullptr, 1024, DM, 0,
                     (g >> 3) * 128, (g & 7) * 128);
        return;
    }

    __shared__ __attribute__((aligned(16))) float slots[NSLOT * SLOTF];
    __shared__ int prod_ctr, cons_ctr;

    const int b = bid >> 3;
    const int h = bid & 7;
    const int tid = threadIdx.x;
    const int wv = tid >> 6, lane = tid & 63;

    if (tid == 0) { prod_ctr = 0; cons_ctr = 0; }
    __syncthreads();   // init only
    if (wv >= 2) return;

    if (wv == 1) {
        // ---------------- producer ----------------
        for (int t0 = 0; t0 < TT; t0 += 4) {
            if (t0 >= NSLOT) {
                int tgt = t0 - 12;
                while (__hip_atomic_load(&cons_ctr, __ATOMIC_ACQUIRE,
                                         __HIP_MEMORY_SCOPE_WORKGROUP) < tgt)
                    __builtin_amdgcn_s_sleep(8);
            }
            float va[4][5]; float pv[4];
            #pragma unroll
            for (int i = 0; i < 4; ++i) {
                const float* prow = proj + (size_t)((t0+i)*BBATCH + b) * NPROJ;
                const float* p5 = prow + h*320;
                va[i][0] = p5[lane];
                va[i][1] = p5[64  + lane];
                va[i][2] = p5[128 + lane];
                va[i][3] = p5[192 + lane];
                va[i][4] = p5[256 + lane];
                pv[i] = (lane < 12) ? prow[KQV + h*12 + lane] : 0.f;
            }
            #pragma unroll
            for (int i = 0; i < 4; ++i) {
                float* sl = slots + (size_t)((t0+i) & (NSLOT-1)) * SLOTF;
                sl[lane]       = va[i][0];
                sl[64  + lane] = va[i][1];
                sl[128 + lane] = va[i][2];
                sl[192 + lane] = va[i][3];
                sl[256 + lane] = va[i][4];
                if (lane < 12) sl[320 + lane] = pv[i];
            }
            if (lane == 0)
                __hip_atomic_store(&prod_ctr, t0 + 4, __ATOMIC_RELEASE,
                                   __HIP_MEMORY_SCOPE_WORKGROUP);
        }
        return;
    }

    // ---------------- consumer ----------------
    float4 fs = *(const float4*)(s_prev + ((size_t)(b*HH + h))*256 + lane*4);
    float4 fk[8];
    #pragma unroll
    for (int r = 0; r < 8; ++r)
        fk[r] = *(const float4*)(tilde_k + (((size_t)b*RR + r)*HH + h)*256 + lane*4);
    float fv[8];
    #pragma unroll
    for (int r = 0; r < 8; ++r)
        fv[r] = tilde_v[(((size_t)b*RR + r)*HH + h)*64 + lane];

    const float PI_ = 3.14159265358979323846f;
    float tk = tick[b];
    float cw[8], sw[8], oc[8], os[8];
    #pragma unroll
    for (int r = 0; r < 8; ++r) {
        float w = -PI_ + (float)r * (2.0f * PI_ / 7.0f);
        cw[r] = cosf(w); sw[r] = sinf(w);
        float a0 = (tk + 1.0f) * w;
        oc[r] = cosf(a0); os[r] = sinf(a0);
    }

    int ta  = term[lane*BBATCH + b];
    int tb_ = term[(64 + lane)*BBATCH + b];

    struct PF { float k, q, v, bt, g; float4 p1, p2, p3; };
    auto loadPF = [&](int t, PF& p) {
        if (t < TT) {
            const float* sl = slots + (size_t)(t & (NSLOT-1)) * SLOTF;
            p.k  = sl[lane];
            p.q  = sl[64  + lane];
            p.v  = sl[128 + lane];
            p.bt = sl[192 + lane];
            p.g  = sl[256 + lane];
            p.p1 = *(const float4*)(sl + 320);
            p.p2 = *(const float4*)(sl + 324);
            p.p3 = *(const float4*)(sl + 328);
        }
    };

    auto step = [&](int t, PF c) {
        int tm = (t < 64) ? __builtin_amdgcn_readlane(ta, t)
                          : __builtin_amdgcn_readlane(tb_, t - 64);
        float mask = 1.0f - (float)tm;
        float kr = fmaxf(c.k, 0.f);
        float qr = fmaxf(c.q, 0.f);
        float sg = sigmoidf_(c.g);
        float p1a[4] = {c.p1.x, c.p1.y, c.p1.z, c.p1.w};
        float p2a[4] = {c.p2.x, c.p2.y, c.p2.z, c.p2.w};
        float p3a[4] = {c.p3.x, c.p3.y, c.p3.z, c.p3.w};
        float qexp[4], kg[4], dg[4];
        #pragma unroll
        for (int j = 0; j < 4; ++j) {
            float kexp = kr * fmaxf(p1a[j], 0.f);
            qexp[j]    = qr * fmaxf(p2a[j], 0.f);
            float gexp = sg * sigmoidf_(p3a[j]);
            kg[j] = kexp * gexp;
            dg[j] = (1.f - gexp) * mask;
        }
        fs.x = dg[0]*fs.x + kg[0];
        fs.y = dg[1]*fs.y + kg[1];
        fs.z = dg[2]*fs.z + kg[2];
        fs.w = dg[3]*fs.w + kg[3];
        float snorm = fs.x*qexp[0] + fs.y*qexp[1] + fs.z*qexp[2] + fs.w*qexp[3];
        float kdq[8];
        #pragma unroll
        for (int r = 0; r < 8; ++r) {
            float4 f = fk[r];
            float o = oc[r];
            f.x = dg[0]*f.x + kg[0]*o;
            f.y = dg[1]*f.y + kg[1]*o;
            f.z = dg[2]*f.z + kg[2]*o;
            f.w = dg[3]*f.w + kg[3]*o;
            fk[r] = f;
            kdq[r] = f.x*qexp[0] + f.y*qexp[1] + f.z*qexp[2] + f.w*qexp[3];
        }
        float sb = sigmoidf_(c.bt);
        float vg = c.v * sb;
        float db = (1.f - sb) * mask;
        #pragma unroll
        for (int r = 0; r < 8; ++r)
            fv[r] = db * fv[r] + vg * oc[r];
        #pragma unroll
        for (int r = 0; r < 8; ++r) {
            float cc = oc[r], ss = os[r];
            oc[r] = cc*cw[r] - ss*sw[r];
            os[r] = ss*cw[r] + cc*sw[r];
        }
        float nrm_u = wave_sum_u(snorm);
        float kdq_u[8];
        #pragma unroll
        for (int r = 0; r < 8; ++r)
            kdq_u[r] = wave_sum_u(kdq[r]);
        float kv = 0.f;
        #pragma unroll
        for (int r = 0; r < 8; ++r)
            kv += fv[r] * kdq_u[r];
        attn[(size_t)(t*BBATCH + b)*DM + h*64 + lane] =
            __float2bfloat16(kv / (16.f * (nrm_u + 1e-6f)));
    };

    while (__hip_atomic_load(&prod_ctr, __ATOMIC_ACQUIRE,
                             __HIP_MEMORY_SCOPE_WORKGROUP) < 8)
        __builtin_amdgcn_s_sleep(2);
    PF pf0, pf1;
    loadPF(0, pf0);
    loadPF(1, pf1);

    for (int t = 0; t < TT; t += 2) {
        if ((t & 3) == 0) {
            if ((t & 7) == 0 && t >= 8 && lane == 0)
                __hip_atomic_store(&cons_ctr, t - 2, __ATOMIC_RELEASE,
                                   __HIP_MEMORY_SCOPE_WORKGROUP);
            int tgt = (t + 8 > TT) ? TT : t + 8;
            while (__hip_atomic_load(&prod_ctr, __ATOMIC_ACQUIRE,
                                     __HIP_MEMORY_SCOPE_WORKGROUP) < tgt)
                __builtin_amdgcn_s_sleep(2);
        }
        PF c0 = pf0; loadPF(t + 2, pf0);
        step(t, c0);
        PF c1 = pf1; loadPF(t + 3, pf1);
        step(t + 1, c1);
    }
}

// ---------------- launch --------------------------------------------------
extern "C" void kernel_launch(void* const* d_in, const int* in_sizes, int n_in,
                              void* d_out, int out_size, void* d_ws, size_t ws_size,
                              hipStream_t stream)
{
    const float* inputs = (const float*)d_in[0];
    const int*   term   = (const int*)  d_in[1];
    const float* tilde_k= (const float*)d_in[2];
    const float* tilde_v= (const float*)d_in[3];
    const float* s_prev = (const float*)d_in[4];
    const float* tick   = (const float*)d_in[5];
    const float* w_proj = (const float*)d_in[6];
    const float* b_proj = (const float*)d_in[7];
    const float* w_attn = (const float*)d_in[8];
    const float* b_attn = (const float*)d_in[9];
    const float* ln1_g  = (const float*)d_in[10];
    const float* ln1_b  = (const float*)d_in[11];
    const float* ln2_g  = (const float*)d_in[12];
    const float* ln2_b  = (const float*)d_in[13];
    const float* gru1_w = (const float*)d_in[14];
    const float* gru1_u = (const float*)d_in[15];
    const float* gru2_w = (const float*)d_in[16];
    const float* gru2_u = (const float*)d_in[17];
    const float* ffc_w1 = (const float*)d_in[18];
    const float* ffc_b1 = (const float*)d_in[19];
    const float* ffc_w2 = (const float*)d_in[20];
    const float* ffc_b2 = (const float*)d_in[21];
    float* out = (float*)d_out;
    float* ws  = (float*)d_ws;

    // ---- f32 region (floats) ----
    float* proj = ws;                       // 4096x2656 (dead after scan)
    float* A1h  = ws + 10878976;            // 4096x512 (tanh-pre)
    float* zb   = ws + 12976128;            // 4096x512
    float* g1   = ws + 15073280;            // 4096x512
    // ---- bf16 region ----
    __hip_bfloat16* bb = (__hip_bfloat16*)(ws + 17170432);
    __hip_bfloat16* wp_bf  = bb + 0;          // 2656x512
    __hip_bfloat16* wat_bf = bb + 1359872;    // 512x512
    __hip_bfloat16* g1w_bf = bb + 1622016;    // 3x512x512
    __hip_bfloat16* g1u_bf = bb + 2408448;
    __hip_bfloat16* g2w_bf = bb + 3194880;
    __hip_bfloat16* g2u_bf = bb + 3981312;
    __hip_bfloat16* fw1_bf = bb + 4767744;    // 2048x512
    __hip_bfloat16* fw2_bf = bb + 5816320;    // 512x2048
    __hip_bfloat16* in_bf  = bb + 6864896;    // 4096x512
    __hip_bfloat16* xn_bf  = bb + 8962048;
    __hip_bfloat16* at_bf  = bb + 11059200;
    __hip_bfloat16* y1_bf  = bb + 13156352;
    __hip_bfloat16* rx_bf  = bb + 15253504;
    __hip_bfloat16* fi_bf  = bb + 17350656;
    __hip_bfloat16* mid_bf = bb + 19447808;   // 4096x2048
    __hip_bfloat16* fo_bf  = bb + 27836416;
    __hip_bfloat16* g1_bf  = bb + 29933568;
    // Bx after bf16 region — never overlaps proj (r6 lesson). Reused for
    // GRU1 (written in scan dispatch, read in stage 5) then GRU2 (written
    // stage 8 ffc1_bx_dual, read stage 10).
    float* Bx = ws + 33185792;   // 4096x1024 -> total ~149.5 MB

    dim3 blk(256);

    // 1. merged f32->bf16 conversions + LN1 (one launch)
    F2B9 fa;
    const float* srcs[9] = {w_proj, w_attn, gru1_w, gru1_u, gru2_w, gru2_u,
                            ffc_w1, ffc_w2, inputs};
    __hip_bfloat16* dsts[9] = {wp_bf, wat_bf, g1w_bf, g1u_bf, g2w_bf, g2u_bf,
                               fw1_bf, fw2_bf, in_bf};
    int quads[9] = {339968, 65536, 196608, 196608, 196608, 196608,
                    262144, 262144, 524288};
    int cum = 0;
    for (int i = 0; i < 9; ++i) { fa.s[i] = srcs[i]; fa.d[i] = dsts[i]; fa.cum[i] = cum; cum += quads[i]; }
    fa.cum[9] = cum;
    f2b_ln_all<<<8752 + MM, blk, 0, stream>>>(fa, inputs, ln1_g, ln1_b, xn_bf);

    // 2. projection
    gemm_bf16<<<dim3(21, 32), blk, 0, stream>>>(xn_bf, wp_bf, b_proj, proj, nullptr, NPROJ, DM, 0);

    // 3. fused scans + attention, with GRU1's Bx GEMM co-scheduled
    scan_attn_fused<<<512, blk, 0, stream>>>(proj, term, tick, tilde_k, tilde_v,
                                             s_prev, at_bf, in_bf, g1u_bf, Bx);

    // 4. attn out-proj (+relu)
    gemm_bf16_64<<<dim3(4, 64), blk, 0, stream>>>(at_bf, wat_bf, b_attn, nullptr, y1_bf, DM, DM, 1);

    // 5. GRU1 A1-GEMM with fused rz epilogue -> rx_bf, zb, A1h
    gemm_gru_rz<<<dim3(12, 32), blk, 0, stream>>>(y1_bf, g1w_bf, Bx, inputs, rx_bf, zb, A1h);

    // 6. GRU1 C2-GEMM with fused final epilogue -> g1 (+bf16 copy)
    gemm_gru_final<<<dim3(4, 64), blk, 0, stream>>>(rx_bf, g1u_bf + 2*DM*DM, A1h, zb, inputs, g1, g1_bf);

    // 7. LN2
    ln_kernel<<<MM, blk, 0, stream>>>(g1, ln2_g, ln2_b, fi_bf);

    // 8. FFC1 + GRU2's Bx GEMM (independent, one launch)
    ffc1_bx_dual<<<dim3(24, 32), blk, 0, stream>>>(fi_bf, fw1_bf, ffc_b1, mid_bf,
                                                   2048, 16,
                                                   g1_bf, g2u_bf, Bx, 1024, DM);

    // 9. FFC2 (+relu)
    gemm_bf16_64<<<dim3(4, 64), blk, 0, stream>>>(mid_bf, fw2_bf, ffc_b2, nullptr, fo_bf, DM, 2048, 1);

    // 10. GRU2 A1-GEMM with fused rz epilogue
    gemm_gru_rz<<<dim3(12, 32), blk, 0, stream>>>(fo_bf, g2w_bf, Bx, g1, rx_bf, zb, A1h);

    // 11. GRU2 C2-GEMM with fused final epilogue -> out
    gemm_gru_final<<<dim3(4, 64), blk, 0, stream>>>(rx_bf, g2u_bf + 2*DM*DM, A1h, zb, g1, out, nullptr);
}

// Round 10
// 480.389 us; speedup vs baseline: 1.0955x; 1.0955x over previous
//
#include <hip/hip_runtime.h>
#include <hip/hip_bf16.h>
#include <math.h>

#define DM   512
#define HH   8
#define RR   8
#define TT   128
#define BBATCH 32
#define MM   (TT*BBATCH)     // 4096 rows
#define NPROJ 2656
#define KQV  2560

typedef __attribute__((ext_vector_type(8))) short bf16x8;
typedef __attribute__((ext_vector_type(4))) float f32x4;

__device__ __forceinline__ float sigmoidf_(float x) {
    return 1.0f / (1.0f + __expf(-x));
}

__device__ __forceinline__ void gload_lds16(const void* g, void* l) {
    __builtin_amdgcn_global_load_lds(
        (const __attribute__((address_space(1))) unsigned int*)g,
        (__attribute__((address_space(3))) unsigned int*)l, 16, 0, 0);
}

// ---- DPP wave64 sum -> uniform value --------------------------------------
template<int CTRL, int RMASK>
__device__ __forceinline__ float dpp_add_(float x) {
    union { float f; int i; } a, b;
    a.f = x;
    b.i = __builtin_amdgcn_update_dpp(0, a.i, CTRL, RMASK, 0xf, true);
    return x + b.f;
}
__device__ __forceinline__ float wave_sum_u(float x) {
    x = dpp_add_<0x111, 0xf>(x);   // row_shr:1
    x = dpp_add_<0x112, 0xf>(x);   // row_shr:2
    x = dpp_add_<0x114, 0xf>(x);   // row_shr:4
    x = dpp_add_<0x118, 0xf>(x);   // row_shr:8
    x = dpp_add_<0x142, 0xa>(x);   // row_bcast:15 -> rows 1,3
    x = dpp_add_<0x143, 0xc>(x);   // row_bcast:31 -> rows 2,3
    union { float f; int i; } s, t;
    s.f = x;
    t.i = __builtin_amdgcn_readlane(s.i, 63);
    return t.f;
}

// ---------------- merged f32->bf16 conversions + LN1 (one launch) ---------
struct F2B9 {
    const float* s[9];
    __hip_bfloat16* d[9];
    int cum[10];
};

__global__ __launch_bounds__(256) void f2b_ln_all(F2B9 a,
    const float* __restrict__ x, const float* __restrict__ g,
    const float* __restrict__ b, __hip_bfloat16* __restrict__ lnout)
{
    if (blockIdx.x < 8752) {
        int q = blockIdx.x * 256 + threadIdx.x;
        if (q >= a.cum[9]) return;
        int s = 0;
        #pragma unroll
        for (int i = 1; i < 9; ++i) s += (q >= a.cum[i]);
        int i4 = (q - a.cum[s]) * 4;
        float4 v = *(const float4*)(a.s[s] + i4);
        __hip_bfloat16* dst = a.d[s] + i4;
        dst[0] = __float2bfloat16(v.x);
        dst[1] = __float2bfloat16(v.y);
        dst[2] = __float2bfloat16(v.z);
        dst[3] = __float2bfloat16(v.w);
        return;
    }
    int row = blockIdx.x - 8752;
    int tid = threadIdx.x;
    const float* xr = x + (size_t)row * DM;
    float2 v = ((const float2*)xr)[tid];
    float s = v.x + v.y;
    #pragma unroll
    for (int off = 32; off; off >>= 1) s += __shfl_down(s, off);
    __shared__ float red[8];
    int wid = tid >> 6, lane = tid & 63;
    if (lane == 0) red[wid] = s;
    __syncthreads();
    if (tid == 0) red[0] = (red[0] + red[1] + red[2] + red[3]) * (1.0f / DM);
    __syncthreads();
    float mean = red[0];
    float dx = v.x - mean, dy = v.y - mean;
    float sq = dx*dx + dy*dy;
    #pragma unroll
    for (int off = 32; off; off >>= 1) sq += __shfl_down(sq, off);
    if (lane == 0) red[4 + wid] = sq;
    __syncthreads();
    if (tid == 0) red[1] = rsqrtf((red[4]+red[5]+red[6]+red[7]) * (1.0f/DM) + 1e-5f);
    __syncthreads();
    float rstd = red[1];
    float2 gg = ((const float2*)g)[tid];
    float2 bb = ((const float2*)b)[tid];
    __hip_bfloat16* orow = lnout + (size_t)row * DM;
    orow[2*tid+0] = __float2bfloat16(dx * rstd * gg.x + bb.x);
    orow[2*tid+1] = __float2bfloat16(dy * rstd * gg.y + bb.y);
}

// ---------------- standalone LayerNorm -> bf16 (LN2 path unused; kept) ----
__global__ __launch_bounds__(256) void ln_kernel(const float* __restrict__ x,
    const float* __restrict__ g, const float* __restrict__ b,
    __hip_bfloat16* __restrict__ out)
{
    int row = blockIdx.x;
    int tid = threadIdx.x;
    const float* xr = x + (size_t)row * DM;
    float2 v = ((const float2*)xr)[tid];
    float s = v.x + v.y;
    #pragma unroll
    for (int off = 32; off; off >>= 1) s += __shfl_down(s, off);
    __shared__ float red[8];
    int wid = tid >> 6, lane = tid & 63;
    if (lane == 0) red[wid] = s;
    __syncthreads();
    if (tid == 0) red[0] = (red[0] + red[1] + red[2] + red[3]) * (1.0f / DM);
    __syncthreads();
    float mean = red[0];
    float dx = v.x - mean, dy = v.y - mean;
    float sq = dx*dx + dy*dy;
    #pragma unroll
    for (int off = 32; off; off >>= 1) sq += __shfl_down(sq, off);
    if (lane == 0) red[4 + wid] = sq;
    __syncthreads();
    if (tid == 0) red[1] = rsqrtf((red[4]+red[5]+red[6]+red[7]) * (1.0f/DM) + 1e-5f);
    __syncthreads();
    float rstd = red[1];
    float2 gg = ((const float2*)g)[tid];
    float2 bb = ((const float2*)b)[tid];
    __hip_bfloat16* orow = out + (size_t)row * DM;
    orow[2*tid+0] = __float2bfloat16(dx * rstd * gg.x + bb.x);
    orow[2*tid+1] = __float2bfloat16(dy * rstd * gg.y + bb.y);
}

// ---------------- bf16 MFMA GEMM core: 128x128 tile, BK=32 ----------------
__device__ __forceinline__ void gemm_core128(
    const __hip_bfloat16* __restrict__ A, const __hip_bfloat16* __restrict__ W,
    const float* __restrict__ bias,
    float* __restrict__ Cf, __hip_bfloat16* __restrict__ Cb,
    int N, int K, int act, int m0, int n0)
{
    __shared__ __attribute__((aligned(16))) __hip_bfloat16 As[8*512];
    __shared__ __attribute__((aligned(16))) __hip_bfloat16 Bs[8*512];
    int tid = threadIdx.x;
    int wave = tid >> 6, lane = tid & 63;
    int wm = (wave >> 1) * 64, wn = (wave & 1) * 64;
    int fr = lane & 15, fq = lane >> 4;

    f32x4 acc[4][4];
    #pragma unroll
    for (int i = 0; i < 4; ++i)
        #pragma unroll
        for (int j = 0; j < 4; ++j)
            acc[i][j] = (f32x4){0.f, 0.f, 0.f, 0.f};

    int sm0 = wave*16 + fr;
    int sm1 = sm0 + 64;
    int wr0 = n0 + sm0; if (wr0 >= N) wr0 = N - 1;
    int wr1 = n0 + sm1; if (wr1 >= N) wr1 = N - 1;
    const __hip_bfloat16* Ag0 = A + (size_t)(m0 + sm0) * K + fq*8;
    const __hip_bfloat16* Ag1 = A + (size_t)(m0 + sm1) * K + fq*8;
    const __hip_bfloat16* Wg0 = W + (size_t)wr0 * K + fq*8;
    const __hip_bfloat16* Wg1 = W + (size_t)wr1 * K + fq*8;

    for (int k0 = 0; k0 < K; k0 += 32) {
        gload_lds16(Ag0 + k0, As + (size_t)wave*512);
        gload_lds16(Ag1 + k0, As + (size_t)(wave+4)*512);
        gload_lds16(Wg0 + k0, Bs + (size_t)wave*512);
        gload_lds16(Wg1 + k0, Bs + (size_t)(wave+4)*512);
        __syncthreads();
        bf16x8 af[4], bfr[4];
        #pragma unroll
        for (int i = 0; i < 4; ++i) {
            af[i]  = *(const bf16x8*)(As + (size_t)(wm/16 + i)*512 + lane*8);
            bfr[i] = *(const bf16x8*)(Bs + (size_t)(wn/16 + i)*512 + lane*8);
        }
        #pragma unroll
        for (int mi = 0; mi < 4; ++mi)
            #pragma unroll
            for (int ni = 0; ni < 4; ++ni)
                acc[mi][ni] = __builtin_amdgcn_mfma_f32_16x16x32_bf16(
                    af[mi], bfr[ni], acc[mi][ni], 0, 0, 0);
        __syncthreads();
    }

    #pragma unroll
    for (int ni = 0; ni < 4; ++ni) {
        int n = n0 + wn + ni*16 + fr;
        bool nok = n < N;
        float bv = (bias && nok) ? bias[n] : 0.f;
        #pragma unroll
        for (int mi = 0; mi < 4; ++mi) {
            #pragma unroll
            for (int r = 0; r < 4; ++r) {
                int m = m0 + wm + mi*16 + fq*4 + r;
                float v = acc[mi][ni][r] + bv;
                if (act) v = fmaxf(v, 0.f);
                if (nok) {
                    size_t idx = (size_t)m * N + n;
                    if (Cf) Cf[idx] = v;
                    if (Cb) Cb[idx] = __float2bfloat16(v);
                }
            }
        }
    }
}

__global__ __launch_bounds__(256) void gemm_bf16(
    const __hip_bfloat16* __restrict__ A, const __hip_bfloat16* __restrict__ W,
    const float* __restrict__ bias,
    float* __restrict__ Cf, __hip_bfloat16* __restrict__ Cb,
    int N, int K, int act)
{
    gemm_core128(A, W, bias, Cf, Cb, N, K, act, blockIdx.y * 128, blockIdx.x * 128);
}

// FFC1 + Bx2 in one launch
__global__ __launch_bounds__(256) void ffc1_bx_dual(
    const __hip_bfloat16* __restrict__ Aa, const __hip_bfloat16* __restrict__ Wa,
    const float* __restrict__ biasA, __hip_bfloat16* __restrict__ CbA,
    int Na, int splitX,
    const __hip_bfloat16* __restrict__ Ab, const __hip_bfloat16* __restrict__ Wb,
    float* __restrict__ CfB, int Nb, int K)
{
    int bx = blockIdx.x;
    if (bx < splitX)
        gemm_core128(Aa, Wa, biasA, nullptr, CbA, Na, K, 1, blockIdx.y*128, bx*128);
    else
        gemm_core128(Ab, Wb, nullptr, CfB, nullptr, Nb, K, 0, blockIdx.y*128, (bx-splitX)*128);
}

// ---------------- 64x128-tile GEMM (N=512 cases: 256 blocks) --------------
__global__ __launch_bounds__(256) void gemm_bf16_64(
    const __hip_bfloat16* __restrict__ A, const __hip_bfloat16* __restrict__ W,
    const float* __restrict__ bias,
    float* __restrict__ Cf, __hip_bfloat16* __restrict__ Cb,
    int N, int K, int act)
{
    __shared__ __attribute__((aligned(16))) __hip_bfloat16 As[4*512];
    __shared__ __attribute__((aligned(16))) __hip_bfloat16 Bs[8*512];
    int tid = threadIdx.x;
    int wave = tid >> 6, lane = tid & 63;
    int m0 = blockIdx.y * 64, n0 = blockIdx.x * 128;
    int wm = (wave >> 1) * 32, wn = (wave & 1) * 64;
    int fr = lane & 15, fq = lane >> 4;

    f32x4 acc[2][4];
    #pragma unroll
    for (int i = 0; i < 2; ++i)
        #pragma unroll
        for (int j = 0; j < 4; ++j)
            acc[i][j] = (f32x4){0.f, 0.f, 0.f, 0.f};

    const __hip_bfloat16* Ag = A + (size_t)(m0 + wave*16 + fr) * K + fq*8;
    int wr0 = n0 + wave*16 + fr; if (wr0 >= N) wr0 = N - 1;
    int wr1 = wr0 + 64;          if (wr1 >= N) wr1 = N - 1;
    const __hip_bfloat16* Wg0 = W + (size_t)wr0 * K + fq*8;
    const __hip_bfloat16* Wg1 = W + (size_t)wr1 * K + fq*8;

    for (int k0 = 0; k0 < K; k0 += 32) {
        gload_lds16(Ag  + k0, As + (size_t)wave*512);
        gload_lds16(Wg0 + k0, Bs + (size_t)wave*512);
        gload_lds16(Wg1 + k0, Bs + (size_t)(wave+4)*512);
        __syncthreads();
        bf16x8 af[2], bfr[4];
        #pragma unroll
        for (int i = 0; i < 2; ++i)
            af[i]  = *(const bf16x8*)(As + (size_t)(wm/16 + i)*512 + lane*8);
        #pragma unroll
        for (int j = 0; j < 4; ++j)
            bfr[j] = *(const bf16x8*)(Bs + (size_t)(wn/16 + j)*512 + lane*8);
        #pragma unroll
        for (int mi = 0; mi < 2; ++mi)
            #pragma unroll
            for (int ni = 0; ni < 4; ++ni)
                acc[mi][ni] = __builtin_amdgcn_mfma_f32_16x16x32_bf16(
                    af[mi], bfr[ni], acc[mi][ni], 0, 0, 0);
        __syncthreads();
    }

    #pragma unroll
    for (int ni = 0; ni < 4; ++ni) {
        int n = n0 + wn + ni*16 + fr;
        bool nok = n < N;
        float bv = (bias && nok) ? bias[n] : 0.f;
        #pragma unroll
        for (int mi = 0; mi < 2; ++mi) {
            #pragma unroll
            for (int r = 0; r < 4; ++r) {
                int m = m0 + wm + mi*16 + fq*4 + r;
                float v = acc[mi][ni][r] + bv;
                if (act) v = fmaxf(v, 0.f);
                if (nok) {
                    size_t idx = (size_t)m * N + n;
                    if (Cf) Cf[idx] = v;
                    if (Cb) Cb[idx] = __float2bfloat16(v);
                }
            }
        }
    }
}

// ---------------- fused scans + attention + co-scheduled Bx GEMM ----------
// Blocks 0..255: scan per (b,h); blocks 256..511: GRU1's Bx GEMM.
// Producer wave now PRECOMPUTES the gates (qexp/kg/dg/vg/db, mask folded)
// and the oscillator occ[8] per t, writing them to the ring — the consumer's
// serial chain is pure FMA scans + DPP reductions. Same fp ops, same order,
// different wave -> bitwise identical to r7.
// Slot layout (floats): qexp[256] @0, kg[256] @256, dg[256] @512,
//                       vg[64] @768, db[64] @832, oc[8] @896. SLOTF=912.
#define NSLOT 16
#define SLOTF 912

__global__ __launch_bounds__(256) void scan_attn_fused(
    const float* __restrict__ proj, const int* __restrict__ term,
    const float* __restrict__ tick, const float* __restrict__ tilde_k,
    const float* __restrict__ tilde_v, const float* __restrict__ s_prev,
    __hip_bfloat16* __restrict__ attn,
    const __hip_bfloat16* __restrict__ gA, const __hip_bfloat16* __restrict__ gW,
    float* __restrict__ gC)
{
    int bid = blockIdx.x;
    if (bid >= 256) {
        int g = bid - 256;
        gemm_core128(gA, gW, nullptr, gC, nullptr, 1024, DM, 0,
                     (g >> 3) * 128, (g & 7) * 128);
        return;
    }

    __shared__ __attribute__((aligned(16))) float slots[NSLOT * SLOTF]; // 58.4 KB
    __shared__ int prod_ctr, cons_ctr;

    const int b = bid >> 3;
    const int h = bid & 7;
    const int tid = threadIdx.x;
    const int wv = tid >> 6, lane = tid & 63;

    if (tid == 0) { prod_ctr = 0; cons_ctr = 0; }
    __syncthreads();   // init only
    if (wv >= 2) return;

    const float PI_ = 3.14159265358979323846f;

    if (wv == 1) {
        // ---------------- producer: load + gate precompute + oscillator ---
        float tk = tick[b];
        int ta  = term[lane*BBATCH + b];
        int tb_ = term[(64 + lane)*BBATCH + b];
        // oscillator for r = lane&7 (identical recurrence to r7 consumer)
        float wv_ = -PI_ + (float)(lane & 7) * (2.0f * PI_ / 7.0f);
        float cwv = cosf(wv_), swv = sinf(wv_);
        float ocv = cosf((tk + 1.0f) * wv_), osv = sinf((tk + 1.0f) * wv_);

        for (int t0 = 0; t0 < TT; t0 += 4) {
            if (t0 >= NSLOT) {
                int tgt = t0 - (NSLOT - 4);
                while (__hip_atomic_load(&cons_ctr, __ATOMIC_ACQUIRE,
                                         __HIP_MEMORY_SCOPE_WORKGROUP) < tgt)
                    __builtin_amdgcn_s_sleep(8);
            }
            float va[4][5]; float4 P1[4], P2[4], P3[4];
            #pragma unroll
            for (int i = 0; i < 4; ++i) {
                const float* prow = proj + (size_t)((t0+i)*BBATCH + b) * NPROJ;
                const float* p5 = prow + h*320;
                va[i][0] = p5[lane];
                va[i][1] = p5[64  + lane];
                va[i][2] = p5[128 + lane];
                va[i][3] = p5[192 + lane];
                va[i][4] = p5[256 + lane];
                const float* pe = prow + KQV + h*12;
                P1[i] = *(const float4*)(pe);
                P2[i] = *(const float4*)(pe + 4);
                P3[i] = *(const float4*)(pe + 8);
            }
            #pragma unroll
            for (int i = 0; i < 4; ++i) {
                int t = t0 + i;
                int tm = (t < 64) ? __builtin_amdgcn_readlane(ta, t)
                                  : __builtin_amdgcn_readlane(tb_, t - 64);
                float mask = 1.0f - (float)tm;
                float kr = fmaxf(va[i][0], 0.f);
                float qr = fmaxf(va[i][1], 0.f);
                float sg = sigmoidf_(va[i][4]);
                float sb = sigmoidf_(va[i][3]);
                float vg = va[i][2] * sb;
                float db = (1.f - sb) * mask;
                float p1a[4] = {P1[i].x, P1[i].y, P1[i].z, P1[i].w};
                float p2a[4] = {P2[i].x, P2[i].y, P2[i].z, P2[i].w};
                float p3a[4] = {P3[i].x, P3[i].y, P3[i].z, P3[i].w};
                float4 qe, kgv, dgv;
                #pragma unroll
                for (int j = 0; j < 4; ++j) {
                    float kexp = kr * fmaxf(p1a[j], 0.f);
                    float qq   = qr * fmaxf(p2a[j], 0.f);
                    float gexp = sg * sigmoidf_(p3a[j]);
                    float kg_  = kexp * gexp;
                    float dg_  = (1.f - gexp) * mask;
                    if (j == 0) { qe.x = qq; kgv.x = kg_; dgv.x = dg_; }
                    if (j == 1) { qe.y = qq; kgv.y = kg_; dgv.y = dg_; }
                    if (j == 2) { qe.z = qq; kgv.z = kg_; dgv.z = dg_; }
                    if (j == 3) { qe.w = qq; kgv.w = kg_; dgv.w = dg_; }
                }
                float* sl = slots + (size_t)(t & (NSLOT-1)) * SLOTF;
                *(float4*)(sl + 4*lane)       = qe;
                *(float4*)(sl + 256 + 4*lane) = kgv;
                *(float4*)(sl + 512 + 4*lane) = dgv;
                sl[768 + lane] = vg;
                sl[832 + lane] = db;
                if (lane < 8) sl[896 + lane] = ocv;
                // rotate for next t (identical to r7 consumer rotation)
                float cc = ocv, ss = osv;
                ocv = cc*cwv - ss*swv;
                osv = ss*cwv + cc*swv;
            }
            if (lane == 0)
                __hip_atomic_store(&prod_ctr, t0 + 4, __ATOMIC_RELEASE,
                                   __HIP_MEMORY_SCOPE_WORKGROUP);
        }
        return;
    }

    // ---------------- consumer: pure FMA scans + DPP reductions ----------
    float4 fs = *(const float4*)(s_prev + ((size_t)(b*HH + h))*256 + lane*4);
    float4 fk[8];
    #pragma unroll
    for (int r = 0; r < 8; ++r)
        fk[r] = *(const float4*)(tilde_k + (((size_t)b*RR + r)*HH + h)*256 + lane*4);
    float fv[8];
    #pragma unroll
    for (int r = 0; r < 8; ++r)
        fv[r] = tilde_v[(((size_t)b*RR + r)*HH + h)*64 + lane];

    struct PF { float4 qe, kg, dg, o0, o1; float vg, db; };
    auto loadPF = [&](int t, PF& p) {
        if (t < TT) {
            const float* sl = slots + (size_t)(t & (NSLOT-1)) * SLOTF;
            p.qe = *(const float4*)(sl + 4*lane);
            p.kg = *(const float4*)(sl + 256 + 4*lane);
            p.dg = *(const float4*)(sl + 512 + 4*lane);
            p.vg = sl[768 + lane];
            p.db = sl[832 + lane];
            p.o0 = *(const float4*)(sl + 896);
            p.o1 = *(const float4*)(sl + 900);
        }
    };

    auto step = [&](int t, PF c) {
        float qexp[4] = {c.qe.x, c.qe.y, c.qe.z, c.qe.w};
        float kg[4]   = {c.kg.x, c.kg.y, c.kg.z, c.kg.w};
        float dg[4]   = {c.dg.x, c.dg.y, c.dg.z, c.dg.w};
        float occ[8]  = {c.o0.x, c.o0.y, c.o0.z, c.o0.w,
                         c.o1.x, c.o1.y, c.o1.z, c.o1.w};
        fs.x = dg[0]*fs.x + kg[0];
        fs.y = dg[1]*fs.y + kg[1];
        fs.z = dg[2]*fs.z + kg[2];
        fs.w = dg[3]*fs.w + kg[3];
        float snorm = fs.x*qexp[0] + fs.y*qexp[1] + fs.z*qexp[2] + fs.w*qexp[3];
        float kdq[8];
        #pragma unroll
        for (int r = 0; r < 8; ++r) {
            float4 f = fk[r];
            float o = occ[r];
            f.x = dg[0]*f.x + kg[0]*o;
            f.y = dg[1]*f.y + kg[1]*o;
            f.z = dg[2]*f.z + kg[2]*o;
            f.w = dg[3]*f.w + kg[3]*o;
            fk[r] = f;
            kdq[r] = f.x*qexp[0] + f.y*qexp[1] + f.z*qexp[2] + f.w*qexp[3];
        }
        #pragma unroll
        for (int r = 0; r < 8; ++r)
            fv[r] = c.db * fv[r] + c.vg * occ[r];
        float nrm_u = wave_sum_u(snorm);
        float kdq_u[8];
        #pragma unroll
        for (int r = 0; r < 8; ++r)
            kdq_u[r] = wave_sum_u(kdq[r]);
        float kv = 0.f;
        #pragma unroll
        for (int r = 0; r < 8; ++r)
            kv += fv[r] * kdq_u[r];
        attn[(size_t)(t*BBATCH + b)*DM + h*64 + lane] =
            __float2bfloat16(kv / (16.f * (nrm_u + 1e-6f)));
    };

    while (__hip_atomic_load(&prod_ctr, __ATOMIC_ACQUIRE,
                             __HIP_MEMORY_SCOPE_WORKGROUP) < 8)
        __builtin_amdgcn_s_sleep(2);
    PF pf0, pf1;
    loadPF(0, pf0);
    loadPF(1, pf1);

    for (int t = 0; t < TT; t += 2) {
        if ((t & 3) == 0) {
            if ((t & 7) == 0 && t >= 8 && lane == 0)
                __hip_atomic_store(&cons_ctr, t - 2, __ATOMIC_RELEASE,
                                   __HIP_MEMORY_SCOPE_WORKGROUP);
            int tgt = (t + 8 > TT) ? TT : t + 8;
            while (__hip_atomic_load(&prod_ctr, __ATOMIC_ACQUIRE,
                                     __HIP_MEMORY_SCOPE_WORKGROUP) < tgt)
                __builtin_amdgcn_s_sleep(2);
        }
        PF c0 = pf0; loadPF(t + 2, pf0);
        step(t, c0);
        PF c1 = pf1; loadPF(t + 3, pf1);
        step(t + 1, c1);
    }
}

// ---------------- GRU elementwise phases (r7 versions — wide, fast) -------
__global__ __launch_bounds__(256) void gru_rz_kernel(const float* __restrict__ A1,
    const float* __restrict__ Bx, const float* __restrict__ x,
    __hip_bfloat16* __restrict__ rx, float* __restrict__ z)
{
    size_t i = (size_t)blockIdx.x * 256 + threadIdx.x;
    size_t m = i >> 9;
    int c = (int)(i & 511);
    float rpre = A1[m*1536 + c]       + Bx[m*1024 + c];
    float zpre = A1[m*1536 + 512 + c] + Bx[m*1024 + 512 + c] - 2.0f;
    rx[i] = __float2bfloat16(sigmoidf_(rpre) * x[i]);
    z[i]  = sigmoidf_(zpre);
}

__global__ __launch_bounds__(256) void gru_final_kernel(const float* __restrict__ A1,
    const float* __restrict__ C2, const float* __restrict__ z,
    const float* __restrict__ x, float* __restrict__ out)
{
    size_t i = (size_t)blockIdx.x * 256 + threadIdx.x;
    size_t m = i >> 9;
    int c = (int)(i & 511);
    float hh = tanhf(A1[m*1536 + 1024 + c] + C2[i]);
    float zz = z[i];
    out[i] = (1.0f - zz) * x[i] + zz * hh;
}

// GRU1 final fused with LN2 (r7 version)
__global__ __launch_bounds__(256) void gru_final_ln(
    const float* __restrict__ A1, const float* __restrict__ C2,
    const float* __restrict__ z, const float* __restrict__ x,
    const float* __restrict__ g, const float* __restrict__ bta,
    float* __restrict__ g1, __hip_bfloat16* __restrict__ g1b,
    __hip_bfloat16* __restrict__ fib)
{
    int row = blockIdx.x;
    int tid = threadIdx.x;
    size_t base = (size_t)row * DM;
    float2 c2v = ((const float2*)(C2 + base))[tid];
    float2 zv  = ((const float2*)(z  + base))[tid];
    float2 xv  = ((const float2*)(x  + base))[tid];
    float2 av  = ((const float2*)(A1 + (size_t)row*1536 + 1024))[tid];
    float h0 = tanhf(av.x + c2v.x);
    float h1 = tanhf(av.y + c2v.y);
    float2 v;
    v.x = (1.0f - zv.x) * xv.x + zv.x * h0;
    v.y = (1.0f - zv.y) * xv.y + zv.y * h1;
    ((float2*)(g1 + base))[tid] = v;
    g1b[base + 2*tid+0] = __float2bfloat16(v.x);
    g1b[base + 2*tid+1] = __float2bfloat16(v.y);

    float s = v.x + v.y;
    #pragma unroll
    for (int off = 32; off; off >>= 1) s += __shfl_down(s, off);
    __shared__ float red[8];
    int wid = tid >> 6, lane = tid & 63;
    if (lane == 0) red[wid] = s;
    __syncthreads();
    if (tid == 0) red[0] = (red[0] + red[1] + red[2] + red[3]) * (1.0f / DM);
    __syncthreads();
    float mean = red[0];
    float dx = v.x - mean, dy = v.y - mean;
    float sq = dx*dx + dy*dy;
    #pragma unroll
    for (int off = 32; off; off >>= 1) sq += __shfl_down(sq, off);
    if (lane == 0) red[4 + wid] = sq;
    __syncthreads();
    if (tid == 0) red[1] = rsqrtf((red[4]+red[5]+red[6]+red[7]) * (1.0f/DM) + 1e-5f);
    __syncthreads();
    float rstd = red[1];
    float2 gg = ((const float2*)g)[tid];
    float2 bb = ((const float2*)bta)[tid];
    fib[base + 2*tid+0] = __float2bfloat16(dx * rstd * gg.x + bb.x);
    fib[base + 2*tid+1] = __float2bfloat16(dy * rstd * gg.y + bb.y);
}

// ---------------- launch --------------------------------------------------
extern "C" void kernel_launch(void* const* d_in, const int* in_sizes, int n_in,
                              void* d_out, int out_size, void* d_ws, size_t ws_size,
                              hipStream_t stream)
{
    const float* inputs = (const float*)d_in[0];
    const int*   term   = (const int*)  d_in[1];
    const float* tilde_k= (const float*)d_in[2];
    const float* tilde_v= (const float*)d_in[3];
    const float* s_prev = (const float*)d_in[4];
    const float* tick   = (const float*)d_in[5];
    const float* w_proj = (const float*)d_in[6];
    const float* b_proj = (const float*)d_in[7];
    const float* w_attn = (const float*)d_in[8];
    const float* b_attn = (const float*)d_in[9];
    const float* ln1_g  = (const float*)d_in[10];
    const float* ln1_b  = (const float*)d_in[11];
    const float* ln2_g  = (const float*)d_in[12];
    const float* ln2_b  = (const float*)d_in[13];
    const float* gru1_w = (const float*)d_in[14];
    const float* gru1_u = (const float*)d_in[15];
    const float* gru2_w = (const float*)d_in[16];
    const float* gru2_u = (const float*)d_in[17];
    const float* ffc_w1 = (const float*)d_in[18];
    const float* ffc_b1 = (const float*)d_in[19];
    const float* ffc_w2 = (const float*)d_in[20];
    const float* ffc_b2 = (const float*)d_in[21];
    float* out = (float*)d_out;
    float* ws  = (float*)d_ws;

    // ---- f32 region (floats) ----
    float* proj = ws;                       // 4096x2656 (dead after scan)
    float* A1   = ws;                       // 4096x1536 (overlays proj; written AFTER scan)
    float* C2   = ws + 10878976;            // 4096x512
    float* zb   = ws + 12976128;            // 4096x512
    float* g1   = ws + 15073280;            // 4096x512
    // ---- bf16 region ----
    __hip_bfloat16* bb = (__hip_bfloat16*)(ws + 17170432);
    __hip_bfloat16* wp_bf  = bb + 0;          // 2656x512
    __hip_bfloat16* wat_bf = bb + 1359872;    // 512x512
    __hip_bfloat16* g1w_bf = bb + 1622016;    // 3x512x512
    __hip_bfloat16* g1u_bf = bb + 2408448;
    __hip_bfloat16* g2w_bf = bb + 3194880;
    __hip_bfloat16* g2u_bf = bb + 3981312;
    __hip_bfloat16* fw1_bf = bb + 4767744;    // 2048x512
    __hip_bfloat16* fw2_bf = bb + 5816320;    // 512x2048
    __hip_bfloat16* in_bf  = bb + 6864896;    // 4096x512
    __hip_bfloat16* xn_bf  = bb + 8962048;
    __hip_bfloat16* at_bf  = bb + 11059200;
    __hip_bfloat16* y1_bf  = bb + 13156352;
    __hip_bfloat16* rx_bf  = bb + 15253504;
    __hip_bfloat16* fi_bf  = bb + 17350656;
    __hip_bfloat16* mid_bf = bb + 19447808;   // 4096x2048
    __hip_bfloat16* fo_bf  = bb + 27836416;
    __hip_bfloat16* g1_bf  = bb + 29933568;
    // Bx after bf16 region — never overlaps proj (r6 lesson).
    float* Bx = ws + 33185792;   // 4096x1024 -> total ~149.5 MB

    dim3 blk(256);

    // 1. merged f32->bf16 conversions + LN1 (one launch)
    F2B9 fa;
    const float* srcs[9] = {w_proj, w_attn, gru1_w, gru1_u, gru2_w, gru2_u,
                            ffc_w1, ffc_w2, inputs};
    __hip_bfloat16* dsts[9] = {wp_bf, wat_bf, g1w_bf, g1u_bf, g2w_bf, g2u_bf,
                               fw1_bf, fw2_bf, in_bf};
    int quads[9] = {339968, 65536, 196608, 196608, 196608, 196608,
                    262144, 262144, 524288};
    int cum = 0;
    for (int i = 0; i < 9; ++i) { fa.s[i] = srcs[i]; fa.d[i] = dsts[i]; fa.cum[i] = cum; cum += quads[i]; }
    fa.cum[9] = cum;
    f2b_ln_all<<<8752 + MM, blk, 0, stream>>>(fa, inputs, ln1_g, ln1_b, xn_bf);

    // 2. projection
    gemm_bf16<<<dim3(21, 32), blk, 0, stream>>>(xn_bf, wp_bf, b_proj, proj, nullptr, NPROJ, DM, 0);

    // 3. fused scans + attention (producer-precompute) + GRU1's Bx GEMM
    scan_attn_fused<<<512, blk, 0, stream>>>(proj, term, tick, tilde_k, tilde_v,
                                             s_prev, at_bf, in_bf, g1u_bf, Bx);

    // 4. attn out-proj (+relu)
    gemm_bf16_64<<<dim3(4, 64), blk, 0, stream>>>(at_bf, wat_bf, b_attn, nullptr, y1_bf, DM, DM, 1);

    // 5. GRU1 A1 GEMM (plain, f32 out)
    gemm_bf16<<<dim3(12, 32), blk, 0, stream>>>(y1_bf, g1w_bf, nullptr, A1, nullptr, 3*DM, DM, 0);
    gru_rz_kernel<<<MM*DM/256, blk, 0, stream>>>(A1, Bx, inputs, rx_bf, zb);
    gemm_bf16_64<<<dim3(4, 64), blk, 0, stream>>>(rx_bf, g1u_bf + 2*DM*DM, nullptr, C2, nullptr, DM, DM, 0);
    gru_final_ln<<<MM, blk, 0, stream>>>(A1, C2, zb, inputs, ln2_g, ln2_b, g1, g1_bf, fi_bf);

    // 6. FFC1 + GRU2's Bx GEMM (one launch)
    ffc1_bx_dual<<<dim3(24, 32), blk, 0, stream>>>(fi_bf, fw1_bf, ffc_b1, mid_bf,
                                                   2048, 16,
                                                   g1_bf, g2u_bf, Bx, 1024, DM);

    // 7. FFC2 (+relu)
    gemm_bf16_64<<<dim3(4, 64), blk, 0, stream>>>(mid_bf, fw2_bf, ffc_b2, nullptr, fo_bf, DM, 2048, 1);

    // 8. GRU2
    gemm_bf16<<<dim3(12, 32), blk, 0, stream>>>(fo_bf, g2w_bf, nullptr, A1, nullptr, 3*DM, DM, 0);
    gru_rz_kernel<<<MM*DM/256, blk, 0, stream>>>(A1, Bx, g1, rx_bf, zb);
    gemm_bf16_64<<<dim3(4, 64), blk, 0, stream>>>(rx_bf, g2u_bf + 2*DM*DM, nullptr, C2, nullptr, DM, DM, 0);
    gru_final_kernel<<<MM*DM/256, blk, 0, stream>>>(A1, C2, zb, g1, out);
}

// Round 11
// 476.561 us; speedup vs baseline: 1.1043x; 1.0080x over previous
//
#include <hip/hip_runtime.h>
#include <hip/hip_bf16.h>
#include <math.h>

#define DM   512
#define HH   8
#define RR   8
#define TT   128
#define BBATCH 32
#define MM   (TT*BBATCH)     // 4096 rows
#define NPROJ 2656
#define KQV  2560

typedef __attribute__((ext_vector_type(8))) short bf16x8;
typedef __attribute__((ext_vector_type(4))) float f32x4;

__device__ __forceinline__ float sigmoidf_(float x) {
    return 1.0f / (1.0f + __expf(-x));
}

__device__ __forceinline__ void gload_lds16(const void* g, void* l) {
    __builtin_amdgcn_global_load_lds(
        (const __attribute__((address_space(1))) unsigned int*)g,
        (__attribute__((address_space(3))) unsigned int*)l, 16, 0, 0);
}

// ---- DPP wave64 sum -> uniform value --------------------------------------
template<int CTRL, int RMASK>
__device__ __forceinline__ float dpp_add_(float x) {
    union { float f; int i; } a, b;
    a.f = x;
    b.i = __builtin_amdgcn_update_dpp(0, a.i, CTRL, RMASK, 0xf, true);
    return x + b.f;
}
__device__ __forceinline__ float wave_sum_u(float x) {
    x = dpp_add_<0x111, 0xf>(x);   // row_shr:1
    x = dpp_add_<0x112, 0xf>(x);   // row_shr:2
    x = dpp_add_<0x114, 0xf>(x);   // row_shr:4
    x = dpp_add_<0x118, 0xf>(x);   // row_shr:8
    x = dpp_add_<0x142, 0xa>(x);   // row_bcast:15 -> rows 1,3
    x = dpp_add_<0x143, 0xc>(x);   // row_bcast:31 -> rows 2,3
    union { float f; int i; } s, t;
    s.f = x;
    t.i = __builtin_amdgcn_readlane(s.i, 63);
    return t.f;
}

// ---------------- merged f32->bf16 conversions + LN1 (one launch) ---------
struct F2B9 {
    const float* s[9];
    __hip_bfloat16* d[9];
    int cum[10];
};

__global__ __launch_bounds__(256) void f2b_ln_all(F2B9 a,
    const float* __restrict__ x, const float* __restrict__ g,
    const float* __restrict__ b, __hip_bfloat16* __restrict__ lnout)
{
    if (blockIdx.x < 8752) {
        int q = blockIdx.x * 256 + threadIdx.x;
        if (q >= a.cum[9]) return;
        int s = 0;
        #pragma unroll
        for (int i = 1; i < 9; ++i) s += (q >= a.cum[i]);
        int i4 = (q - a.cum[s]) * 4;
        float4 v = *(const float4*)(a.s[s] + i4);
        __hip_bfloat16* dst = a.d[s] + i4;
        dst[0] = __float2bfloat16(v.x);
        dst[1] = __float2bfloat16(v.y);
        dst[2] = __float2bfloat16(v.z);
        dst[3] = __float2bfloat16(v.w);
        return;
    }
    int row = blockIdx.x - 8752;
    int tid = threadIdx.x;
    const float* xr = x + (size_t)row * DM;
    float2 v = ((const float2*)xr)[tid];
    float s = v.x + v.y;
    #pragma unroll
    for (int off = 32; off; off >>= 1) s += __shfl_down(s, off);
    __shared__ float red[8];
    int wid = tid >> 6, lane = tid & 63;
    if (lane == 0) red[wid] = s;
    __syncthreads();
    if (tid == 0) red[0] = (red[0] + red[1] + red[2] + red[3]) * (1.0f / DM);
    __syncthreads();
    float mean = red[0];
    float dx = v.x - mean, dy = v.y - mean;
    float sq = dx*dx + dy*dy;
    #pragma unroll
    for (int off = 32; off; off >>= 1) sq += __shfl_down(sq, off);
    if (lane == 0) red[4 + wid] = sq;
    __syncthreads();
    if (tid == 0) red[1] = rsqrtf((red[4]+red[5]+red[6]+red[7]) * (1.0f/DM) + 1e-5f);
    __syncthreads();
    float rstd = red[1];
    float2 gg = ((const float2*)g)[tid];
    float2 bb = ((const float2*)b)[tid];
    __hip_bfloat16* orow = lnout + (size_t)row * DM;
    orow[2*tid+0] = __float2bfloat16(dx * rstd * gg.x + bb.x);
    orow[2*tid+1] = __float2bfloat16(dy * rstd * gg.y + bb.y);
}

// ---------------- bf16 MFMA GEMM core: 128x128 tile, BK=32 ----------------
// LDS buffers passed in (callers provide static or dynamic shared).
__device__ __forceinline__ void gemm_core128(
    const __hip_bfloat16* __restrict__ A, const __hip_bfloat16* __restrict__ W,
    const float* __restrict__ bias,
    float* __restrict__ Cf, __hip_bfloat16* __restrict__ Cb,
    int N, int K, int act, int m0, int n0,
    __hip_bfloat16* As, __hip_bfloat16* Bs)
{
    int tid = threadIdx.x;
    int wave = tid >> 6, lane = tid & 63;
    int wm = (wave >> 1) * 64, wn = (wave & 1) * 64;
    int fr = lane & 15, fq = lane >> 4;

    f32x4 acc[4][4];
    #pragma unroll
    for (int i = 0; i < 4; ++i)
        #pragma unroll
        for (int j = 0; j < 4; ++j)
            acc[i][j] = (f32x4){0.f, 0.f, 0.f, 0.f};

    int sm0 = wave*16 + fr;
    int sm1 = sm0 + 64;
    int wr0 = n0 + sm0; if (wr0 >= N) wr0 = N - 1;
    int wr1 = n0 + sm1; if (wr1 >= N) wr1 = N - 1;
    const __hip_bfloat16* Ag0 = A + (size_t)(m0 + sm0) * K + fq*8;
    const __hip_bfloat16* Ag1 = A + (size_t)(m0 + sm1) * K + fq*8;
    const __hip_bfloat16* Wg0 = W + (size_t)wr0 * K + fq*8;
    const __hip_bfloat16* Wg1 = W + (size_t)wr1 * K + fq*8;

    for (int k0 = 0; k0 < K; k0 += 32) {
        gload_lds16(Ag0 + k0, As + (size_t)wave*512);
        gload_lds16(Ag1 + k0, As + (size_t)(wave+4)*512);
        gload_lds16(Wg0 + k0, Bs + (size_t)wave*512);
        gload_lds16(Wg1 + k0, Bs + (size_t)(wave+4)*512);
        __syncthreads();
        bf16x8 af[4], bfr[4];
        #pragma unroll
        for (int i = 0; i < 4; ++i) {
            af[i]  = *(const bf16x8*)(As + (size_t)(wm/16 + i)*512 + lane*8);
            bfr[i] = *(const bf16x8*)(Bs + (size_t)(wn/16 + i)*512 + lane*8);
        }
        #pragma unroll
        for (int mi = 0; mi < 4; ++mi)
            #pragma unroll
            for (int ni = 0; ni < 4; ++ni)
                acc[mi][ni] = __builtin_amdgcn_mfma_f32_16x16x32_bf16(
                    af[mi], bfr[ni], acc[mi][ni], 0, 0, 0);
        __syncthreads();
    }

    #pragma unroll
    for (int ni = 0; ni < 4; ++ni) {
        int n = n0 + wn + ni*16 + fr;
        bool nok = n < N;
        float bv = (bias && nok) ? bias[n] : 0.f;
        #pragma unroll
        for (int mi = 0; mi < 4; ++mi) {
            #pragma unroll
            for (int r = 0; r < 4; ++r) {
                int m = m0 + wm + mi*16 + fq*4 + r;
                float v = acc[mi][ni][r] + bv;
                if (act) v = fmaxf(v, 0.f);
                if (nok) {
                    size_t idx = (size_t)m * N + n;
                    if (Cf) Cf[idx] = v;
                    if (Cb) Cb[idx] = __float2bfloat16(v);
                }
            }
        }
    }
}

__global__ __launch_bounds__(256) void gemm_bf16(
    const __hip_bfloat16* __restrict__ A, const __hip_bfloat16* __restrict__ W,
    const float* __restrict__ bias,
    float* __restrict__ Cf, __hip_bfloat16* __restrict__ Cb,
    int N, int K, int act)
{
    __shared__ __attribute__((aligned(16))) __hip_bfloat16 As[8*512];
    __shared__ __attribute__((aligned(16))) __hip_bfloat16 Bs[8*512];
    gemm_core128(A, W, bias, Cf, Cb, N, K, act, blockIdx.y * 128, blockIdx.x * 128, As, Bs);
}

// FFC1 + Bx2 in one launch
__global__ __launch_bounds__(256) void ffc1_bx_dual(
    const __hip_bfloat16* __restrict__ Aa, const __hip_bfloat16* __restrict__ Wa,
    const float* __restrict__ biasA, __hip_bfloat16* __restrict__ CbA,
    int Na, int splitX,
    const __hip_bfloat16* __restrict__ Ab, const __hip_bfloat16* __restrict__ Wb,
    float* __restrict__ CfB, int Nb, int K)
{
    __shared__ __attribute__((aligned(16))) __hip_bfloat16 As[8*512];
    __shared__ __attribute__((aligned(16))) __hip_bfloat16 Bs[8*512];
    int bx = blockIdx.x;
    if (bx < splitX)
        gemm_core128(Aa, Wa, biasA, nullptr, CbA, Na, K, 1, blockIdx.y*128, bx*128, As, Bs);
    else
        gemm_core128(Ab, Wb, nullptr, CfB, nullptr, Nb, K, 0, blockIdx.y*128, (bx-splitX)*128, As, Bs);
}

// ---------------- 64x128-tile GEMM (N=512 cases: 256 blocks) --------------
__global__ __launch_bounds__(256) void gemm_bf16_64(
    const __hip_bfloat16* __restrict__ A, const __hip_bfloat16* __restrict__ W,
    const float* __restrict__ bias,
    float* __restrict__ Cf, __hip_bfloat16* __restrict__ Cb,
    int N, int K, int act)
{
    __shared__ __attribute__((aligned(16))) __hip_bfloat16 As[4*512];
    __shared__ __attribute__((aligned(16))) __hip_bfloat16 Bs[8*512];
    int tid = threadIdx.x;
    int wave = tid >> 6, lane = tid & 63;
    int m0 = blockIdx.y * 64, n0 = blockIdx.x * 128;
    int wm = (wave >> 1) * 32, wn = (wave & 1) * 64;
    int fr = lane & 15, fq = lane >> 4;

    f32x4 acc[2][4];
    #pragma unroll
    for (int i = 0; i < 2; ++i)
        #pragma unroll
        for (int j = 0; j < 4; ++j)
            acc[i][j] = (f32x4){0.f, 0.f, 0.f, 0.f};

    const __hip_bfloat16* Ag = A + (size_t)(m0 + wave*16 + fr) * K + fq*8;
    int wr0 = n0 + wave*16 + fr; if (wr0 >= N) wr0 = N - 1;
    int wr1 = wr0 + 64;          if (wr1 >= N) wr1 = N - 1;
    const __hip_bfloat16* Wg0 = W + (size_t)wr0 * K + fq*8;
    const __hip_bfloat16* Wg1 = W + (size_t)wr1 * K + fq*8;

    for (int k0 = 0; k0 < K; k0 += 32) {
        gload_lds16(Ag  + k0, As + (size_t)wave*512);
        gload_lds16(Wg0 + k0, Bs + (size_t)wave*512);
        gload_lds16(Wg1 + k0, Bs + (size_t)(wave+4)*512);
        __syncthreads();
        bf16x8 af[2], bfr[4];
        #pragma unroll
        for (int i = 0; i < 2; ++i)
            af[i]  = *(const bf16x8*)(As + (size_t)(wm/16 + i)*512 + lane*8);
        #pragma unroll
        for (int j = 0; j < 4; ++j)
            bfr[j] = *(const bf16x8*)(Bs + (size_t)(wn/16 + j)*512 + lane*8);
        #pragma unroll
        for (int mi = 0; mi < 2; ++mi)
            #pragma unroll
            for (int ni = 0; ni < 4; ++ni)
                acc[mi][ni] = __builtin_amdgcn_mfma_f32_16x16x32_bf16(
                    af[mi], bfr[ni], acc[mi][ni], 0, 0, 0);
        __syncthreads();
    }

    #pragma unroll
    for (int ni = 0; ni < 4; ++ni) {
        int n = n0 + wn + ni*16 + fr;
        bool nok = n < N;
        float bv = (bias && nok) ? bias[n] : 0.f;
        #pragma unroll
        for (int mi = 0; mi < 2; ++mi) {
            #pragma unroll
            for (int r = 0; r < 4; ++r) {
                int m = m0 + wm + mi*16 + fq*4 + r;
                float v = acc[mi][ni][r] + bv;
                if (act) v = fmaxf(v, 0.f);
                if (nok) {
                    size_t idx = (size_t)m * N + n;
                    if (Cf) Cf[idx] = v;
                    if (Cb) Cb[idx] = __float2bfloat16(v);
                }
            }
        }
    }
}

// ---------------- fused scans + attention + co-scheduled Bx GEMM ----------
// Blocks 0..255: scan per (b,h) with a 3-stage wave pipeline:
//   waves 2,3 (load): stream raw proj slices -> 8-slot LDS raw ring
//                     (keeps ~2 groups of global loads in flight)
//   wave 1 (gates):   raw ring -> gate math (bitwise r10 order) -> gate ring
//   wave 0 (consumer): FMA scans + DPP reductions (unchanged)
// Blocks 256..511: GRU1's Bx GEMM. Dynamic shared memory (union layout) so
// scan (69 KB) and GEMM (16 KB) don't sum -> 2 blocks/CU preserved.
#define NSLOT 16
#define SLOTF 912
#define RSLOT 8
#define RSLOTF 336

__global__ __launch_bounds__(256) void scan_attn_fused(
    const float* __restrict__ proj, const int* __restrict__ term,
    const float* __restrict__ tick, const float* __restrict__ tilde_k,
    const float* __restrict__ tilde_v, const float* __restrict__ s_prev,
    __hip_bfloat16* __restrict__ attn,
    const __hip_bfloat16* __restrict__ gA, const __hip_bfloat16* __restrict__ gW,
    float* __restrict__ gC)
{
    extern __shared__ __attribute__((aligned(16))) char smem_dyn[];
    int bid = blockIdx.x;
    if (bid >= 256) {
        __hip_bfloat16* As = (__hip_bfloat16*)smem_dyn;
        __hip_bfloat16* Bs = As + 8*512;
        int g = bid - 256;
        gemm_core128(gA, gW, nullptr, gC, nullptr, 1024, DM, 0,
                     (g >> 3) * 128, (g & 7) * 128, As, Bs);
        return;
    }

    float* slots    = (float*)smem_dyn;                  // 16*912
    float* raw      = slots + NSLOT*SLOTF;               // 8*336
    int*   raw_flag = (int*)(raw + RSLOT*RSLOTF);        // 32
    int*   ctrs     = raw_flag + 32;                     // prod, cons

    const int b = bid >> 3;
    const int h = bid & 7;
    const int tid = threadIdx.x;
    const int wv = tid >> 6, lane = tid & 63;

    if (tid == 0) { ctrs[0] = 0; ctrs[1] = 0; }
    if (tid < 32) raw_flag[tid] = 0;
    __syncthreads();   // init only
    int* prod_ctr = &ctrs[0];
    int* cons_ctr = &ctrs[1];

    const float PI_ = 3.14159265358979323846f;

    if (wv >= 2) {
        // ---------------- load waves: global -> raw ring ----------------
        for (int g = wv - 2; g < TT/4; g += 2) {
            int t0 = g * 4;
            if (t0 >= RSLOT) {
                // raw slots (t0..t0+3)&7 were consumed once gates t0-8..t0-5
                // are published: prod_ctr >= t0-4
                while (__hip_atomic_load(prod_ctr, __ATOMIC_ACQUIRE,
                                         __HIP_MEMORY_SCOPE_WORKGROUP) < t0 - 4)
                    __builtin_amdgcn_s_sleep(1);
            }
            float va[4][5]; float pv[4];
            #pragma unroll
            for (int i = 0; i < 4; ++i) {
                const float* prow = proj + (size_t)((t0+i)*BBATCH + b) * NPROJ;
                const float* p5 = prow + h*320;
                va[i][0] = p5[lane];
                va[i][1] = p5[64  + lane];
                va[i][2] = p5[128 + lane];
                va[i][3] = p5[192 + lane];
                va[i][4] = p5[256 + lane];
                pv[i] = (lane < 12) ? prow[KQV + h*12 + lane] : 0.f;
            }
            #pragma unroll
            for (int i = 0; i < 4; ++i) {
                float* rs = raw + (size_t)((t0+i) & (RSLOT-1)) * RSLOTF;
                rs[lane]       = va[i][0];
                rs[64  + lane] = va[i][1];
                rs[128 + lane] = va[i][2];
                rs[192 + lane] = va[i][3];
                rs[256 + lane] = va[i][4];
                if (lane < 12) rs[320 + lane] = pv[i];
            }
            if (lane == 0)
                __hip_atomic_store(&raw_flag[g], 1, __ATOMIC_RELEASE,
                                   __HIP_MEMORY_SCOPE_WORKGROUP);
        }
        return;
    }

    if (wv == 1) {
        // ---------------- gate producer: raw ring -> gate ring -----------
        // Math identical to r10 producer (bitwise): same order, same rotation.
        float tk = tick[b];
        int ta  = term[lane*BBATCH + b];
        int tb_ = term[(64 + lane)*BBATCH + b];
        float wv_ = -PI_ + (float)(lane & 7) * (2.0f * PI_ / 7.0f);
        float cwv = cosf(wv_), swv = sinf(wv_);
        float ocv = cosf((tk + 1.0f) * wv_), osv = sinf((tk + 1.0f) * wv_);

        for (int t0 = 0; t0 < TT; t0 += 4) {
            if (t0 >= NSLOT) {
                while (__hip_atomic_load(cons_ctr, __ATOMIC_ACQUIRE,
                                         __HIP_MEMORY_SCOPE_WORKGROUP) < t0 - (NSLOT - 4))
                    __builtin_amdgcn_s_sleep(1);
            }
            int g = t0 >> 2;
            while (__hip_atomic_load(&raw_flag[g], __ATOMIC_ACQUIRE,
                                     __HIP_MEMORY_SCOPE_WORKGROUP) == 0)
                __builtin_amdgcn_s_sleep(1);
            float va[4][5]; float4 P1[4], P2[4], P3[4];
            #pragma unroll
            for (int i = 0; i < 4; ++i) {
                const float* rs = raw + (size_t)((t0+i) & (RSLOT-1)) * RSLOTF;
                va[i][0] = rs[lane];
                va[i][1] = rs[64  + lane];
                va[i][2] = rs[128 + lane];
                va[i][3] = rs[192 + lane];
                va[i][4] = rs[256 + lane];
                P1[i] = *(const float4*)(rs + 320);
                P2[i] = *(const float4*)(rs + 324);
                P3[i] = *(const float4*)(rs + 328);
            }
            #pragma unroll
            for (int i = 0; i < 4; ++i) {
                int t = t0 + i;
                int tm = (t < 64) ? __builtin_amdgcn_readlane(ta, t)
                                  : __builtin_amdgcn_readlane(tb_, t - 64);
                float mask = 1.0f - (float)tm;
                float kr = fmaxf(va[i][0], 0.f);
                float qr = fmaxf(va[i][1], 0.f);
                float sg = sigmoidf_(va[i][4]);
                float sb = sigmoidf_(va[i][3]);
                float vg = va[i][2] * sb;
                float db = (1.f - sb) * mask;
                float p1a[4] = {P1[i].x, P1[i].y, P1[i].z, P1[i].w};
                float p2a[4] = {P2[i].x, P2[i].y, P2[i].z, P2[i].w};
                float p3a[4] = {P3[i].x, P3[i].y, P3[i].z, P3[i].w};
                float4 qe, kgv, dgv;
                #pragma unroll
                for (int j = 0; j < 4; ++j) {
                    float kexp = kr * fmaxf(p1a[j], 0.f);
                    float qq   = qr * fmaxf(p2a[j], 0.f);
                    float gexp = sg * sigmoidf_(p3a[j]);
                    float kg_  = kexp * gexp;
                    float dg_  = (1.f - gexp) * mask;
                    if (j == 0) { qe.x = qq; kgv.x = kg_; dgv.x = dg_; }
                    if (j == 1) { qe.y = qq; kgv.y = kg_; dgv.y = dg_; }
                    if (j == 2) { qe.z = qq; kgv.z = kg_; dgv.z = dg_; }
                    if (j == 3) { qe.w = qq; kgv.w = kg_; dgv.w = dg_; }
                }
                float* sl = slots + (size_t)(t & (NSLOT-1)) * SLOTF;
                *(float4*)(sl + 4*lane)       = qe;
                *(float4*)(sl + 256 + 4*lane) = kgv;
                *(float4*)(sl + 512 + 4*lane) = dgv;
                sl[768 + lane] = vg;
                sl[832 + lane] = db;
                if (lane < 8) sl[896 + lane] = ocv;
                float cc = ocv, ss = osv;
                ocv = cc*cwv - ss*swv;
                osv = ss*cwv + cc*swv;
            }
            if (lane == 0)
                __hip_atomic_store(prod_ctr, t0 + 4, __ATOMIC_RELEASE,
                                   __HIP_MEMORY_SCOPE_WORKGROUP);
        }
        return;
    }

    // ---------------- consumer: pure FMA scans + DPP reductions ----------
    float4 fs = *(const float4*)(s_prev + ((size_t)(b*HH + h))*256 + lane*4);
    float4 fk[8];
    #pragma unroll
    for (int r = 0; r < 8; ++r)
        fk[r] = *(const float4*)(tilde_k + (((size_t)b*RR + r)*HH + h)*256 + lane*4);
    float fv[8];
    #pragma unroll
    for (int r = 0; r < 8; ++r)
        fv[r] = tilde_v[(((size_t)b*RR + r)*HH + h)*64 + lane];

    struct PF { float4 qe, kg, dg, o0, o1; float vg, db; };
    auto loadPF = [&](int t, PF& p) {
        if (t < TT) {
            const float* sl = slots + (size_t)(t & (NSLOT-1)) * SLOTF;
            p.qe = *(const float4*)(sl + 4*lane);
            p.kg = *(const float4*)(sl + 256 + 4*lane);
            p.dg = *(const float4*)(sl + 512 + 4*lane);
            p.vg = sl[768 + lane];
            p.db = sl[832 + lane];
            p.o0 = *(const float4*)(sl + 896);
            p.o1 = *(const float4*)(sl + 900);
        }
    };

    auto step = [&](int t, PF c) {
        float qexp[4] = {c.qe.x, c.qe.y, c.qe.z, c.qe.w};
        float kg[4]   = {c.kg.x, c.kg.y, c.kg.z, c.kg.w};
        float dg[4]   = {c.dg.x, c.dg.y, c.dg.z, c.dg.w};
        float occ[8]  = {c.o0.x, c.o0.y, c.o0.z, c.o0.w,
                         c.o1.x, c.o1.y, c.o1.z, c.o1.w};
        fs.x = dg[0]*fs.x + kg[0];
        fs.y = dg[1]*fs.y + kg[1];
        fs.z = dg[2]*fs.z + kg[2];
        fs.w = dg[3]*fs.w + kg[3];
        float snorm = fs.x*qexp[0] + fs.y*qexp[1] + fs.z*qexp[2] + fs.w*qexp[3];
        float kdq[8];
        #pragma unroll
        for (int r = 0; r < 8; ++r) {
            float4 f = fk[r];
            float o = occ[r];
            f.x = dg[0]*f.x + kg[0]*o;
            f.y = dg[1]*f.y + kg[1]*o;
            f.z = dg[2]*f.z + kg[2]*o;
            f.w = dg[3]*f.w + kg[3]*o;
            fk[r] = f;
            kdq[r] = f.x*qexp[0] + f.y*qexp[1] + f.z*qexp[2] + f.w*qexp[3];
        }
        #pragma unroll
        for (int r = 0; r < 8; ++r)
            fv[r] = c.db * fv[r] + c.vg * occ[r];
        float nrm_u = wave_sum_u(snorm);
        float kdq_u[8];
        #pragma unroll
        for (int r = 0; r < 8; ++r)
            kdq_u[r] = wave_sum_u(kdq[r]);
        float kv = 0.f;
        #pragma unroll
        for (int r = 0; r < 8; ++r)
            kv += fv[r] * kdq_u[r];
        attn[(size_t)(t*BBATCH + b)*DM + h*64 + lane] =
            __float2bfloat16(kv / (16.f * (nrm_u + 1e-6f)));
    };

    while (__hip_atomic_load(prod_ctr, __ATOMIC_ACQUIRE,
                             __HIP_MEMORY_SCOPE_WORKGROUP) < 8)
        __builtin_amdgcn_s_sleep(1);
    PF pf0, pf1;
    loadPF(0, pf0);
    loadPF(1, pf1);

    for (int t = 0; t < TT; t += 2) {
        if ((t & 3) == 0) {
            if ((t & 7) == 0 && t >= 8 && lane == 0)
                __hip_atomic_store(cons_ctr, t - 2, __ATOMIC_RELEASE,
                                   __HIP_MEMORY_SCOPE_WORKGROUP);
            int tgt = (t + 8 > TT) ? TT : t + 8;
            while (__hip_atomic_load(prod_ctr, __ATOMIC_ACQUIRE,
                                     __HIP_MEMORY_SCOPE_WORKGROUP) < tgt)
                __builtin_amdgcn_s_sleep(1);
        }
        PF c0 = pf0; loadPF(t + 2, pf0);
        step(t, c0);
        PF c1 = pf1; loadPF(t + 3, pf1);
        step(t + 1, c1);
    }
}

// ---------------- GRU elementwise phases --------------------------------
__global__ __launch_bounds__(256) void gru_rz_kernel(const float* __restrict__ A1,
    const float* __restrict__ Bx, const float* __restrict__ x,
    __hip_bfloat16* __restrict__ rx, float* __restrict__ z)
{
    size_t i = (size_t)blockIdx.x * 256 + threadIdx.x;
    size_t m = i >> 9;
    int c = (int)(i & 511);
    float rpre = A1[m*1536 + c]       + Bx[m*1024 + c];
    float zpre = A1[m*1536 + 512 + c] + Bx[m*1024 + 512 + c] - 2.0f;
    rx[i] = __float2bfloat16(sigmoidf_(rpre) * x[i]);
    z[i]  = sigmoidf_(zpre);
}

__global__ __launch_bounds__(256) void gru_final_kernel(const float* __restrict__ A1,
    const float* __restrict__ C2, const float* __restrict__ z,
    const float* __restrict__ x, float* __restrict__ out)
{
    size_t i = (size_t)blockIdx.x * 256 + threadIdx.x;
    size_t m = i >> 9;
    int c = (int)(i & 511);
    float hh = tanhf(A1[m*1536 + 1024 + c] + C2[i]);
    float zz = z[i];
    out[i] = (1.0f - zz) * x[i] + zz * hh;
}

// GRU1 final fused with LN2
__global__ __launch_bounds__(256) void gru_final_ln(
    const float* __restrict__ A1, const float* __restrict__ C2,
    const float* __restrict__ z, const float* __restrict__ x,
    const float* __restrict__ g, const float* __restrict__ bta,
    float* __restrict__ g1, __hip_bfloat16* __restrict__ g1b,
    __hip_bfloat16* __restrict__ fib)
{
    int row = blockIdx.x;
    int tid = threadIdx.x;
    size_t base = (size_t)row * DM;
    float2 c2v = ((const float2*)(C2 + base))[tid];
    float2 zv  = ((const float2*)(z  + base))[tid];
    float2 xv  = ((const float2*)(x  + base))[tid];
    float2 av  = ((const float2*)(A1 + (size_t)row*1536 + 1024))[tid];
    float h0 = tanhf(av.x + c2v.x);
    float h1 = tanhf(av.y + c2v.y);
    float2 v;
    v.x = (1.0f - zv.x) * xv.x + zv.x * h0;
    v.y = (1.0f - zv.y) * xv.y + zv.y * h1;
    ((float2*)(g1 + base))[tid] = v;
    g1b[base + 2*tid+0] = __float2bfloat16(v.x);
    g1b[base + 2*tid+1] = __float2bfloat16(v.y);

    float s = v.x + v.y;
    #pragma unroll
    for (int off = 32; off; off >>= 1) s += __shfl_down(s, off);
    __shared__ float red[8];
    int wid = tid >> 6, lane = tid & 63;
    if (lane == 0) red[wid] = s;
    __syncthreads();
    if (tid == 0) red[0] = (red[0] + red[1] + red[2] + red[3]) * (1.0f / DM);
    __syncthreads();
    float mean = red[0];
    float dx = v.x - mean, dy = v.y - mean;
    float sq = dx*dx + dy*dy;
    #pragma unroll
    for (int off = 32; off; off >>= 1) sq += __shfl_down(sq, off);
    if (lane == 0) red[4 + wid] = sq;
    __syncthreads();
    if (tid == 0) red[1] = rsqrtf((red[4]+red[5]+red[6]+red[7]) * (1.0f/DM) + 1e-5f);
    __syncthreads();
    float rstd = red[1];
    float2 gg = ((const float2*)g)[tid];
    float2 bb = ((const float2*)bta)[tid];
    fib[base + 2*tid+0] = __float2bfloat16(dx * rstd * gg.x + bb.x);
    fib[base + 2*tid+1] = __float2bfloat16(dy * rstd * gg.y + bb.y);
}

// ---------------- launch --------------------------------------------------
extern "C" void kernel_launch(void* const* d_in, const int* in_sizes, int n_in,
                              void* d_out, int out_size, void* d_ws, size_t ws_size,
                              hipStream_t stream)
{
    const float* inputs = (const float*)d_in[0];
    const int*   term   = (const int*)  d_in[1];
    const float* tilde_k= (const float*)d_in[2];
    const float* tilde_v= (const float*)d_in[3];
    const float* s_prev = (const float*)d_in[4];
    const float* tick   = (const float*)d_in[5];
    const float* w_proj = (const float*)d_in[6];
    const float* b_proj = (const float*)d_in[7];
    const float* w_attn = (const float*)d_in[8];
    const float* b_attn = (const float*)d_in[9];
    const float* ln1_g  = (const float*)d_in[10];
    const float* ln1_b  = (const float*)d_in[11];
    const float* ln2_g  = (const float*)d_in[12];
    const float* ln2_b  = (const float*)d_in[13];
    const float* gru1_w = (const float*)d_in[14];
    const float* gru1_u = (const float*)d_in[15];
    const float* gru2_w = (const float*)d_in[16];
    const float* gru2_u = (const float*)d_in[17];
    const float* ffc_w1 = (const float*)d_in[18];
    const float* ffc_b1 = (const float*)d_in[19];
    const float* ffc_w2 = (const float*)d_in[20];
    const float* ffc_b2 = (const float*)d_in[21];
    float* out = (float*)d_out;
    float* ws  = (float*)d_ws;

    // ---- f32 region (floats) ----
    float* proj = ws;                       // 4096x2656 (dead after scan)
    float* A1   = ws;                       // 4096x1536 (overlays proj; written AFTER scan)
    float* C2   = ws + 10878976;            // 4096x512
    float* zb   = ws + 12976128;            // 4096x512
    float* g1   = ws + 15073280;            // 4096x512
    // ---- bf16 region ----
    __hip_bfloat16* bb = (__hip_bfloat16*)(ws + 17170432);
    __hip_bfloat16* wp_bf  = bb + 0;          // 2656x512
    __hip_bfloat16* wat_bf = bb + 1359872;    // 512x512
    __hip_bfloat16* g1w_bf = bb + 1622016;    // 3x512x512
    __hip_bfloat16* g1u_bf = bb + 2408448;
    __hip_bfloat16* g2w_bf = bb + 3194880;
    __hip_bfloat16* g2u_bf = bb + 3981312;
    __hip_bfloat16* fw1_bf = bb + 4767744;    // 2048x512
    __hip_bfloat16* fw2_bf = bb + 5816320;    // 512x2048
    __hip_bfloat16* in_bf  = bb + 6864896;    // 4096x512
    __hip_bfloat16* xn_bf  = bb + 8962048;
    __hip_bfloat16* at_bf  = bb + 11059200;
    __hip_bfloat16* y1_bf  = bb + 13156352;
    __hip_bfloat16* rx_bf  = bb + 15253504;
    __hip_bfloat16* fi_bf  = bb + 17350656;
    __hip_bfloat16* mid_bf = bb + 19447808;   // 4096x2048
    __hip_bfloat16* fo_bf  = bb + 27836416;
    __hip_bfloat16* g1_bf  = bb + 29933568;
    // Bx after bf16 region — never overlaps proj (r6 lesson).
    float* Bx = ws + 33185792;   // 4096x1024 -> total ~149.5 MB

    dim3 blk(256);

    // 1. merged f32->bf16 conversions + LN1 (one launch)
    F2B9 fa;
    const float* srcs[9] = {w_proj, w_attn, gru1_w, gru1_u, gru2_w, gru2_u,
                            ffc_w1, ffc_w2, inputs};
    __hip_bfloat16* dsts[9] = {wp_bf, wat_bf, g1w_bf, g1u_bf, g2w_bf, g2u_bf,
                               fw1_bf, fw2_bf, in_bf};
    int quads[9] = {339968, 65536, 196608, 196608, 196608, 196608,
                    262144, 262144, 524288};
    int cum = 0;
    for (int i = 0; i < 9; ++i) { fa.s[i] = srcs[i]; fa.d[i] = dsts[i]; fa.cum[i] = cum; cum += quads[i]; }
    fa.cum[9] = cum;
    f2b_ln_all<<<8752 + MM, blk, 0, stream>>>(fa, inputs, ln1_g, ln1_b, xn_bf);

    // 2. projection
    gemm_bf16<<<dim3(21, 32), blk, 0, stream>>>(xn_bf, wp_bf, b_proj, proj, nullptr, NPROJ, DM, 0);

    // 3. fused scans + attention (3-stage wave pipeline) + GRU1's Bx GEMM
    //    dynamic LDS: max(scan 69.3 KB, gemm 16 KB)
    size_t dyn = (size_t)(NSLOT*SLOTF + RSLOT*RSLOTF + 64) * 4;
    scan_attn_fused<<<512, blk, dyn, stream>>>(proj, term, tick, tilde_k, tilde_v,
                                               s_prev, at_bf, in_bf, g1u_bf, Bx);

    // 4. attn out-proj (+relu)
    gemm_bf16_64<<<dim3(4, 64), blk, 0, stream>>>(at_bf, wat_bf, b_attn, nullptr, y1_bf, DM, DM, 1);

    // 5. GRU1
    gemm_bf16<<<dim3(12, 32), blk, 0, stream>>>(y1_bf, g1w_bf, nullptr, A1, nullptr, 3*DM, DM, 0);
    gru_rz_kernel<<<MM*DM/256, blk, 0, stream>>>(A1, Bx, inputs, rx_bf, zb);
    gemm_bf16_64<<<dim3(4, 64), blk, 0, stream>>>(rx_bf, g1u_bf + 2*DM*DM, nullptr, C2, nullptr, DM, DM, 0);
    gru_final_ln<<<MM, blk, 0, stream>>>(A1, C2, zb, inputs, ln2_g, ln2_b, g1, g1_bf, fi_bf);

    // 6. FFC1 + GRU2's Bx GEMM (one launch)
    ffc1_bx_dual<<<dim3(24, 32), blk, 0, stream>>>(fi_bf, fw1_bf, ffc_b1, mid_bf,
                                                   2048, 16,
                                                   g1_bf, g2u_bf, Bx, 1024, DM);

    // 7. FFC2 (+relu)
    gemm_bf16_64<<<dim3(4, 64), blk, 0, stream>>>(mid_bf, fw2_bf, ffc_b2, nullptr, fo_bf, DM, 2048, 1);

    // 8. GRU2
    gemm_bf16<<<dim3(12, 32), blk, 0, stream>>>(fo_bf, g2w_bf, nullptr, A1, nullptr, 3*DM, DM, 0);
    gru_rz_kernel<<<MM*DM/256, blk, 0, stream>>>(A1, Bx, g1, rx_bf, zb);
    gemm_bf16_64<<<dim3(4, 64), blk, 0, stream>>>(rx_bf, g2u_bf + 2*DM*DM, nullptr, C2, nullptr, DM, DM, 0);
    gru_final_kernel<<<MM*DM/256, blk, 0, stream>>>(A1, C2, zb, g1, out);
}

// Round 14
// 474.770 us; speedup vs baseline: 1.1085x; 1.0038x over previous
//
#include <hip/hip_runtime.h>
#include <hip/hip_bf16.h>
#include <math.h>

#define DM   512
#define HH   8
#define RR   8
#define TT   128
#define BBATCH 32
#define MM   (TT*BBATCH)     // 4096 rows
#define NPROJ 2656
#define KQV  2560

typedef __attribute__((ext_vector_type(8))) short bf16x8;
typedef __attribute__((ext_vector_type(4))) float f32x4;

__device__ __forceinline__ float sigmoidf_(float x) {
    return 1.0f / (1.0f + __expf(-x));
}

__device__ __forceinline__ void gload_lds16(const void* g, void* l) {
    __builtin_amdgcn_global_load_lds(
        (const __attribute__((address_space(1))) unsigned int*)g,
        (__attribute__((address_space(3))) unsigned int*)l, 16, 0, 0);
}

// ---- DPP wave64 sum -> uniform value --------------------------------------
template<int CTRL, int RMASK>
__device__ __forceinline__ float dpp_add_(float x) {
    union { float f; int i; } a, b;
    a.f = x;
    b.i = __builtin_amdgcn_update_dpp(0, a.i, CTRL, RMASK, 0xf, true);
    return x + b.f;
}
__device__ __forceinline__ float wave_sum_u(float x) {
    x = dpp_add_<0x111, 0xf>(x);
    x = dpp_add_<0x112, 0xf>(x);
    x = dpp_add_<0x114, 0xf>(x);
    x = dpp_add_<0x118, 0xf>(x);
    x = dpp_add_<0x142, 0xa>(x);
    x = dpp_add_<0x143, 0xc>(x);
    union { float f; int i; } s, t;
    s.f = x;
    t.i = __builtin_amdgcn_readlane(s.i, 63);
    return t.f;
}

// ---------------- merged f32->bf16 conversions + LN1 (one launch) ---------
struct F2B9 {
    const float* s[9];
    __hip_bfloat16* d[9];
    int cum[10];
};

__global__ __launch_bounds__(256) void f2b_ln_all(F2B9 a,
    const float* __restrict__ x, const float* __restrict__ g,
    const float* __restrict__ b, __hip_bfloat16* __restrict__ lnout)
{
    if (blockIdx.x < 8752) {
        int q = blockIdx.x * 256 + threadIdx.x;
        if (q >= a.cum[9]) return;
        int s = 0;
        #pragma unroll
        for (int i = 1; i < 9; ++i) s += (q >= a.cum[i]);
        int i4 = (q - a.cum[s]) * 4;
        float4 v = *(const float4*)(a.s[s] + i4);
        __hip_bfloat16* dst = a.d[s] + i4;
        dst[0] = __float2bfloat16(v.x);
        dst[1] = __float2bfloat16(v.y);
        dst[2] = __float2bfloat16(v.z);
        dst[3] = __float2bfloat16(v.w);
        return;
    }
    int row = blockIdx.x - 8752;
    int tid = threadIdx.x;
    const float* xr = x + (size_t)row * DM;
    float2 v = ((const float2*)xr)[tid];
    float s = v.x + v.y;
    #pragma unroll
    for (int off = 32; off; off >>= 1) s += __shfl_down(s, off);
    __shared__ float red[8];
    int wid = tid >> 6, lane = tid & 63;
    if (lane == 0) red[wid] = s;
    __syncthreads();
    if (tid == 0) red[0] = (red[0] + red[1] + red[2] + red[3]) * (1.0f / DM);
    __syncthreads();
    float mean = red[0];
    float dx = v.x - mean, dy = v.y - mean;
    float sq = dx*dx + dy*dy;
    #pragma unroll
    for (int off = 32; off; off >>= 1) sq += __shfl_down(sq, off);
    if (lane == 0) red[4 + wid] = sq;
    __syncthreads();
    if (tid == 0) red[1] = rsqrtf((red[4]+red[5]+red[6]+red[7]) * (1.0f/DM) + 1e-5f);
    __syncthreads();
    float rstd = red[1];
    float2 gg = ((const float2*)g)[tid];
    float2 bb = ((const float2*)b)[tid];
    __hip_bfloat16* orow = lnout + (size_t)row * DM;
    orow[2*tid+0] = __float2bfloat16(dx * rstd * gg.x + bb.x);
    orow[2*tid+1] = __float2bfloat16(dy * rstd * gg.y + bb.y);
}

// ---------------- standalone LayerNorm -> bf16 (kept for reference) -------
__global__ __launch_bounds__(256) void ln_kernel(const float* __restrict__ x,
    const float* __restrict__ g, const float* __restrict__ b,
    __hip_bfloat16* __restrict__ out)
{
    int row = blockIdx.x;
    int tid = threadIdx.x;
    const float* xr = x + (size_t)row * DM;
    float2 v = ((const float2*)xr)[tid];
    float s = v.x + v.y;
    #pragma unroll
    for (int off = 32; off; off >>= 1) s += __shfl_down(s, off);
    __shared__ float red[8];
    int wid = tid >> 6, lane = tid & 63;
    if (lane == 0) red[wid] = s;
    __syncthreads();
    if (tid == 0) red[0] = (red[0] + red[1] + red[2] + red[3]) * (1.0f / DM);
    __syncthreads();
    float mean = red[0];
    float dx = v.x - mean, dy = v.y - mean;
    float sq = dx*dx + dy*dy;
    #pragma unroll
    for (int off = 32; off; off >>= 1) sq += __shfl_down(sq, off);
    if (lane == 0) red[4 + wid] = sq;
    __syncthreads();
    if (tid == 0) red[1] = rsqrtf((red[4]+red[5]+red[6]+red[7]) * (1.0f/DM) + 1e-5f);
    __syncthreads();
    float rstd = red[1];
    float2 gg = ((const float2*)g)[tid];
    float2 bb = ((const float2*)b)[tid];
    __hip_bfloat16* orow = out + (size_t)row * DM;
    orow[2*tid+0] = __float2bfloat16(dx * rstd * gg.x + bb.x);
    orow[2*tid+1] = __float2bfloat16(dy * rstd * gg.y + bb.y);
}

// ---------------- bf16 MFMA GEMM core: 128x128 tile, BK=32 ----------------
// LDS buffers passed in (callers provide static or dynamic shared).
__device__ __forceinline__ void gemm_core128(
    const __hip_bfloat16* __restrict__ A, const __hip_bfloat16* __restrict__ W,
    const float* __restrict__ bias,
    float* __restrict__ Cf, __hip_bfloat16* __restrict__ Cb,
    int N, int K, int act, int m0, int n0,
    __hip_bfloat16* As, __hip_bfloat16* Bs)
{
    int tid = threadIdx.x;
    int wave = tid >> 6, lane = tid & 63;
    int wm = (wave >> 1) * 64, wn = (wave & 1) * 64;
    int fr = lane & 15, fq = lane >> 4;

    f32x4 acc[4][4];
    #pragma unroll
    for (int i = 0; i < 4; ++i)
        #pragma unroll
        for (int j = 0; j < 4; ++j)
            acc[i][j] = (f32x4){0.f, 0.f, 0.f, 0.f};

    int sm0 = wave*16 + fr;
    int sm1 = sm0 + 64;
    int wr0 = n0 + sm0; if (wr0 >= N) wr0 = N - 1;
    int wr1 = n0 + sm1; if (wr1 >= N) wr1 = N - 1;
    const __hip_bfloat16* Ag0 = A + (size_t)(m0 + sm0) * K + fq*8;
    const __hip_bfloat16* Ag1 = A + (size_t)(m0 + sm1) * K + fq*8;
    const __hip_bfloat16* Wg0 = W + (size_t)wr0 * K + fq*8;
    const __hip_bfloat16* Wg1 = W + (size_t)wr1 * K + fq*8;

    for (int k0 = 0; k0 < K; k0 += 32) {
        gload_lds16(Ag0 + k0, As + (size_t)wave*512);
        gload_lds16(Ag1 + k0, As + (size_t)(wave+4)*512);
        gload_lds16(Wg0 + k0, Bs + (size_t)wave*512);
        gload_lds16(Wg1 + k0, Bs + (size_t)(wave+4)*512);
        __syncthreads();
        bf16x8 af[4], bfr[4];
        #pragma unroll
        for (int i = 0; i < 4; ++i) {
            af[i]  = *(const bf16x8*)(As + (size_t)(wm/16 + i)*512 + lane*8);
            bfr[i] = *(const bf16x8*)(Bs + (size_t)(wn/16 + i)*512 + lane*8);
        }
        #pragma unroll
        for (int mi = 0; mi < 4; ++mi)
            #pragma unroll
            for (int ni = 0; ni < 4; ++ni)
                acc[mi][ni] = __builtin_amdgcn_mfma_f32_16x16x32_bf16(
                    af[mi], bfr[ni], acc[mi][ni], 0, 0, 0);
        __syncthreads();
    }

    #pragma unroll
    for (int ni = 0; ni < 4; ++ni) {
        int n = n0 + wn + ni*16 + fr;
        bool nok = n < N;
        float bv = (bias && nok) ? bias[n] : 0.f;
        #pragma unroll
        for (int mi = 0; mi < 4; ++mi) {
            #pragma unroll
            for (int r = 0; r < 4; ++r) {
                int m = m0 + wm + mi*16 + fq*4 + r;
                float v = acc[mi][ni][r] + bv;
                if (act) v = fmaxf(v, 0.f);
                if (nok) {
                    size_t idx = (size_t)m * N + n;
                    if (Cf) Cf[idx] = v;
                    if (Cb) Cb[idx] = __float2bfloat16(v);
                }
            }
        }
    }
}

__global__ __launch_bounds__(256) void gemm_bf16(
    const __hip_bfloat16* __restrict__ A, const __hip_bfloat16* __restrict__ W,
    const float* __restrict__ bias,
    float* __restrict__ Cf, __hip_bfloat16* __restrict__ Cb,
    int N, int K, int act)
{
    __shared__ __attribute__((aligned(16))) __hip_bfloat16 As[8*512];
    __shared__ __attribute__((aligned(16))) __hip_bfloat16 Bs[8*512];
    gemm_core128(A, W, bias, Cf, Cb, N, K, act, blockIdx.y * 128, blockIdx.x * 128, As, Bs);
}

// FFC1 + Bx2 in one launch
__global__ __launch_bounds__(256) void ffc1_bx_dual(
    const __hip_bfloat16* __restrict__ Aa, const __hip_bfloat16* __restrict__ Wa,
    const float* __restrict__ biasA, __hip_bfloat16* __restrict__ CbA,
    int Na, int splitX,
    const __hip_bfloat16* __restrict__ Ab, const __hip_bfloat16* __restrict__ Wb,
    float* __restrict__ CfB, int Nb, int K)
{
    __shared__ __attribute__((aligned(16))) __hip_bfloat16 As[8*512];
    __shared__ __attribute__((aligned(16))) __hip_bfloat16 Bs[8*512];
    int bx = blockIdx.x;
    if (bx < splitX)
        gemm_core128(Aa, Wa, biasA, nullptr, CbA, Na, K, 1, blockIdx.y*128, bx*128, As, Bs);
    else
        gemm_core128(Ab, Wb, nullptr, CfB, nullptr, Nb, K, 0, blockIdx.y*128, (bx-splitX)*128, As, Bs);
}

// ---------------- 64x128-tile GEMM (N=512 cases: 256 blocks) --------------
__global__ __launch_bounds__(256) void gemm_bf16_64(
    const __hip_bfloat16* __restrict__ A, const __hip_bfloat16* __restrict__ W,
    const float* __restrict__ bias,
    float* __restrict__ Cf, __hip_bfloat16* __restrict__ Cb,
    int N, int K, int act)
{
    __shared__ __attribute__((aligned(16))) __hip_bfloat16 As[4*512];
    __shared__ __attribute__((aligned(16))) __hip_bfloat16 Bs[8*512];
    int tid = threadIdx.x;
    int wave = tid >> 6, lane = tid & 63;
    int m0 = blockIdx.y * 64, n0 = blockIdx.x * 128;
    int wm = (wave >> 1) * 32, wn = (wave & 1) * 64;
    int fr = lane & 15, fq = lane >> 4;

    f32x4 acc[2][4];
    #pragma unroll
    for (int i = 0; i < 2; ++i)
        #pragma unroll
        for (int j = 0; j < 4; ++j)
            acc[i][j] = (f32x4){0.f, 0.f, 0.f, 0.f};

    const __hip_bfloat16* Ag = A + (size_t)(m0 + wave*16 + fr) * K + fq*8;
    int wr0 = n0 + wave*16 + fr; if (wr0 >= N) wr0 = N - 1;
    int wr1 = wr0 + 64;          if (wr1 >= N) wr1 = N - 1;
    const __hip_bfloat16* Wg0 = W + (size_t)wr0 * K + fq*8;
    const __hip_bfloat16* Wg1 = W + (size_t)wr1 * K + fq*8;

    for (int k0 = 0; k0 < K; k0 += 32) {
        gload_lds16(Ag  + k0, As + (size_t)wave*512);
        gload_lds16(Wg0 + k0, Bs + (size_t)wave*512);
        gload_lds16(Wg1 + k0, Bs + (size_t)(wave+4)*512);
        __syncthreads();
        bf16x8 af[2], bfr[4];
        #pragma unroll
        for (int i = 0; i < 2; ++i)
            af[i]  = *(const bf16x8*)(As + (size_t)(wm/16 + i)*512 + lane*8);
        #pragma unroll
        for (int j = 0; j < 4; ++j)
            bfr[j] = *(const bf16x8*)(Bs + (size_t)(wn/16 + j)*512 + lane*8);
        #pragma unroll
        for (int mi = 0; mi < 2; ++mi)
            #pragma unroll
            for (int ni = 0; ni < 4; ++ni)
                acc[mi][ni] = __builtin_amdgcn_mfma_f32_16x16x32_bf16(
                    af[mi], bfr[ni], acc[mi][ni], 0, 0, 0);
        __syncthreads();
    }

    #pragma unroll
    for (int ni = 0; ni < 4; ++ni) {
        int n = n0 + wn + ni*16 + fr;
        bool nok = n < N;
        float bv = (bias && nok) ? bias[n] : 0.f;
        #pragma unroll
        for (int mi = 0; mi < 2; ++mi) {
            #pragma unroll
            for (int r = 0; r < 4; ++r) {
                int m = m0 + wm + mi*16 + fq*4 + r;
                float v = acc[mi][ni][r] + bv;
                if (act) v = fmaxf(v, 0.f);
                if (nok) {
                    size_t idx = (size_t)m * N + n;
                    if (Cf) Cf[idx] = v;
                    if (Cb) Cb[idx] = __float2bfloat16(v);
                }
            }
        }
    }
}

// ---------------- fused scans + attention + co-scheduled Bx GEMM ----------
// Blocks 0..255: scan per (b,h) with a 3-stage wave pipeline:
//   waves 2,3 (load): stream raw proj slices -> 8-slot LDS raw ring
//   wave 1 (gates):   raw ring -> gate math -> gate ring
//   wave 0 (consumer): FMA scans + DPP reductions
// Blocks 256..511: GRU1's Bx GEMM. Dynamic shared memory (union layout).
#define NSLOT 16
#define SLOTF 912
#define RSLOT 8
#define RSLOTF 336

__global__ __launch_bounds__(256) void scan_attn_fused(
    const float* __restrict__ proj, const int* __restrict__ term,
    const float* __restrict__ tick, const float* __restrict__ tilde_k,
    const float* __restrict__ tilde_v, const float* __restrict__ s_prev,
    __hip_bfloat16* __restrict__ attn,
    const __hip_bfloat16* __restrict__ gA, const __hip_bfloat16* __restrict__ gW,
    float* __restrict__ gC)
{
    extern __shared__ __attribute__((aligned(16))) char smem_dyn[];
    int bid = blockIdx.x;
    if (bid >= 256) {
        __hip_bfloat16* As = (__hip_bfloat16*)smem_dyn;
        __hip_bfloat16* Bs = As + 8*512;
        int g = bid - 256;
        gemm_core128(gA, gW, nullptr, gC, nullptr, 1024, DM, 0,
                     (g >> 3) * 128, (g & 7) * 128, As, Bs);
        return;
    }

    float* slots    = (float*)smem_dyn;                  // 16*912
    float* raw      = slots + NSLOT*SLOTF;               // 8*336
    int*   raw_flag = (int*)(raw + RSLOT*RSLOTF);        // 32
    int*   ctrs     = raw_flag + 32;                     // prod, cons

    const int b = bid >> 3;
    const int h = bid & 7;
    const int tid = threadIdx.x;
    const int wv = tid >> 6, lane = tid & 63;

    if (tid == 0) { ctrs[0] = 0; ctrs[1] = 0; }
    if (tid < 32) raw_flag[tid] = 0;
    __syncthreads();   // init only
    int* prod_ctr = &ctrs[0];
    int* cons_ctr = &ctrs[1];

    const float PI_ = 3.14159265358979323846f;

    if (wv >= 2) {
        // ---------------- load waves: global -> raw ring ----------------
        for (int g = wv - 2; g < TT/4; g += 2) {
            int t0 = g * 4;
            if (t0 >= RSLOT) {
                while (__hip_atomic_load(prod_ctr, __ATOMIC_ACQUIRE,
                                         __HIP_MEMORY_SCOPE_WORKGROUP) < t0 - 4)
                    __builtin_amdgcn_s_sleep(1);
            }
            float va[4][5]; float pv[4];
            #pragma unroll
            for (int i = 0; i < 4; ++i) {
                const float* prow = proj + (size_t)((t0+i)*BBATCH + b) * NPROJ;
                const float* p5 = prow + h*320;
                va[i][0] = p5[lane];
                va[i][1] = p5[64  + lane];
                va[i][2] = p5[128 + lane];
                va[i][3] = p5[192 + lane];
                va[i][4] = p5[256 + lane];
                pv[i] = (lane < 12) ? prow[KQV + h*12 + lane] : 0.f;
            }
            #pragma unroll
            for (int i = 0; i < 4; ++i) {
                float* rs = raw + (size_t)((t0+i) & (RSLOT-1)) * RSLOTF;
                rs[lane]       = va[i][0];
                rs[64  + lane] = va[i][1];
                rs[128 + lane] = va[i][2];
                rs[192 + lane] = va[i][3];
                rs[256 + lane] = va[i][4];
                if (lane < 12) rs[320 + lane] = pv[i];
            }
            if (lane == 0)
                __hip_atomic_store(&raw_flag[g], 1, __ATOMIC_RELEASE,
                                   __HIP_MEMORY_SCOPE_WORKGROUP);
        }
        return;
    }

    if (wv == 1) {
        // ---------------- gate producer: raw ring -> gate ring -----------
        float tk = tick[b];
        int ta  = term[lane*BBATCH + b];
        int tb_ = term[(64 + lane)*BBATCH + b];
        float wv_ = -PI_ + (float)(lane & 7) * (2.0f * PI_ / 7.0f);
        float cwv = cosf(wv_), swv = sinf(wv_);
        float ocv = cosf((tk + 1.0f) * wv_), osv = sinf((tk + 1.0f) * wv_);

        for (int t0 = 0; t0 < TT; t0 += 4) {
            if (t0 >= NSLOT) {
                while (__hip_atomic_load(cons_ctr, __ATOMIC_ACQUIRE,
                                         __HIP_MEMORY_SCOPE_WORKGROUP) < t0 - (NSLOT - 4))
                    __builtin_amdgcn_s_sleep(1);
            }
            int g = t0 >> 2;
            while (__hip_atomic_load(&raw_flag[g], __ATOMIC_ACQUIRE,
                                     __HIP_MEMORY_SCOPE_WORKGROUP) == 0)
                __builtin_amdgcn_s_sleep(1);
            float va[4][5]; float4 P1[4], P2[4], P3[4];
            #pragma unroll
            for (int i = 0; i < 4; ++i) {
                const float* rs = raw + (size_t)((t0+i) & (RSLOT-1)) * RSLOTF;
                va[i][0] = rs[lane];
                va[i][1] = rs[64  + lane];
                va[i][2] = rs[128 + lane];
                va[i][3] = rs[192 + lane];
                va[i][4] = rs[256 + lane];
                P1[i] = *(const float4*)(rs + 320);
                P2[i] = *(const float4*)(rs + 324);
                P3[i] = *(const float4*)(rs + 328);
            }
            #pragma unroll
            for (int i = 0; i < 4; ++i) {
                int t = t0 + i;
                int tm = (t < 64) ? __builtin_amdgcn_readlane(ta, t)
                                  : __builtin_amdgcn_readlane(tb_, t - 64);
                float mask = 1.0f - (float)tm;
                float kr = fmaxf(va[i][0], 0.f);
                float qr = fmaxf(va[i][1], 0.f);
                float sg = sigmoidf_(va[i][4]);
                float sb = sigmoidf_(va[i][3]);
                float vg = va[i][2] * sb;
                float db = (1.f - sb) * mask;
                float p1a[4] = {P1[i].x, P1[i].y, P1[i].z, P1[i].w};
                float p2a[4] = {P2[i].x, P2[i].y, P2[i].z, P2[i].w};
                float p3a[4] = {P3[i].x, P3[i].y, P3[i].z, P3[i].w};
                float4 qe, kgv, dgv;
                #pragma unroll
                for (int j = 0; j < 4; ++j) {
                    float kexp = kr * fmaxf(p1a[j], 0.f);
                    float qq   = qr * fmaxf(p2a[j], 0.f);
                    float gexp = sg * sigmoidf_(p3a[j]);
                    float kg_  = kexp * gexp;
                    float dg_  = (1.f - gexp) * mask;
                    if (j == 0) { qe.x = qq; kgv.x = kg_; dgv.x = dg_; }
                    if (j == 1) { qe.y = qq; kgv.y = kg_; dgv.y = dg_; }
                    if (j == 2) { qe.z = qq; kgv.z = kg_; dgv.z = dg_; }
                    if (j == 3) { qe.w = qq; kgv.w = kg_; dgv.w = dg_; }
                }
                float* sl = slots + (size_t)(t & (NSLOT-1)) * SLOTF;
                *(float4*)(sl + 4*lane)       = qe;
                *(float4*)(sl + 256 + 4*lane) = kgv;
                *(float4*)(sl + 512 + 4*lane) = dgv;
                sl[768 + lane] = vg;
                sl[832 + lane] = db;
                if (lane < 8) sl[896 + lane] = ocv;
                float cc = ocv, ss = osv;
                ocv = cc*cwv - ss*swv;
                osv = ss*cwv + cc*swv;
            }
            if (lane == 0)
                __hip_atomic_store(prod_ctr, t0 + 4, __ATOMIC_RELEASE,
                                   __HIP_MEMORY_SCOPE_WORKGROUP);
        }
        return;
    }

    // ---------------- consumer: pure FMA scans + DPP reductions ----------
    float4 fs = *(const float4*)(s_prev + ((size_t)(b*HH + h))*256 + lane*4);
    float4 fk[8];
    #pragma unroll
    for (int r = 0; r < 8; ++r)
        fk[r] = *(const float4*)(tilde_k + (((size_t)b*RR + r)*HH + h)*256 + lane*4);
    float fv[8];
    #pragma unroll
    for (int r = 0; r < 8; ++r)
        fv[r] = tilde_v[(((size_t)b*RR + r)*HH + h)*64 + lane];

    struct PF { float4 qe, kg, dg, o0, o1; float vg, db; };
    auto loadPF = [&](int t, PF& p) {
        if (t < TT) {
            const float* sl = slots + (size_t)(t & (NSLOT-1)) * SLOTF;
            p.qe = *(const float4*)(sl + 4*lane);
            p.kg = *(const float4*)(sl + 256 + 4*lane);
            p.dg = *(const float4*)(sl + 512 + 4*lane);
            p.vg = sl[768 + lane];
            p.db = sl[832 + lane];
            p.o0 = *(const float4*)(sl + 896);
            p.o1 = *(const float4*)(sl + 900);
        }
    };

    auto step = [&](int t, PF c) {
        float qexp[4] = {c.qe.x, c.qe.y, c.qe.z, c.qe.w};
        float kg[4]   = {c.kg.x, c.kg.y, c.kg.z, c.kg.w};
        float dg[4]   = {c.dg.x, c.dg.y, c.dg.z, c.dg.w};
        float occ[8]  = {c.o0.x, c.o0.y, c.o0.z, c.o0.w,
                         c.o1.x, c.o1.y, c.o1.z, c.o1.w};
        fs.x = dg[0]*fs.x + kg[0];
        fs.y = dg[1]*fs.y + kg[1];
        fs.z = dg[2]*fs.z + kg[2];
        fs.w = dg[3]*fs.w + kg[3];
        float snorm = fs.x*qexp[0] + fs.y*qexp[1] + fs.z*qexp[2] + fs.w*qexp[3];
        float kdq[8];
        #pragma unroll
        for (int r = 0; r < 8; ++r) {
            float4 f = fk[r];
            float o = occ[r];
            f.x = dg[0]*f.x + kg[0]*o;
            f.y = dg[1]*f.y + kg[1]*o;
            f.z = dg[2]*f.z + kg[2]*o;
            f.w = dg[3]*f.w + kg[3]*o;
            fk[r] = f;
            kdq[r] = f.x*qexp[0] + f.y*qexp[1] + f.z*qexp[2] + f.w*qexp[3];
        }
        #pragma unroll
        for (int r = 0; r < 8; ++r)
            fv[r] = c.db * fv[r] + c.vg * occ[r];
        float nrm_u = wave_sum_u(snorm);
        float kdq_u[8];
        #pragma unroll
        for (int r = 0; r < 8; ++r)
            kdq_u[r] = wave_sum_u(kdq[r]);
        float kv = 0.f;
        #pragma unroll
        for (int r = 0; r < 8; ++r)
            kv += fv[r] * kdq_u[r];
        attn[(size_t)(t*BBATCH + b)*DM + h*64 + lane] =
            __float2bfloat16(kv / (16.f * (nrm_u + 1e-6f)));
    };

    while (__hip_atomic_load(prod_ctr, __ATOMIC_ACQUIRE,
                             __HIP_MEMORY_SCOPE_WORKGROUP) < 8)
        __builtin_amdgcn_s_sleep(1);
    PF pf0, pf1;
    loadPF(0, pf0);
    loadPF(1, pf1);

    for (int t = 0; t < TT; t += 2) {
        if ((t & 3) == 0) {
            if ((t & 7) == 0 && t >= 8 && lane == 0)
                __hip_atomic_store(cons_ctr, t - 2, __ATOMIC_RELEASE,
                                   __HIP_MEMORY_SCOPE_WORKGROUP);
            int tgt = (t + 8 > TT) ? TT : t + 8;
            while (__hip_atomic_load(prod_ctr, __ATOMIC_ACQUIRE,
                                     __HIP_MEMORY_SCOPE_WORKGROUP) < tgt)
                __builtin_amdgcn_s_sleep(1);
        }
        PF c0 = pf0; loadPF(t + 2, pf0);
        step(t, c0);
        PF c1 = pf1; loadPF(t + 3, pf1);
        step(t + 1, c1);
    }
}

// ---------------- GRU elementwise phases --------------------------------
__global__ __launch_bounds__(256) void gru_rz_kernel(const float* __restrict__ A1,
    const float* __restrict__ Bx, const float* __restrict__ x,
    __hip_bfloat16* __restrict__ rx, float* __restrict__ z)
{
    size_t i = (size_t)blockIdx.x * 256 + threadIdx.x;
    size_t m = i >> 9;
    int c = (int)(i & 511);
    float rpre = A1[m*1536 + c]       + Bx[m*1024 + c];
    float zpre = A1[m*1536 + 512 + c] + Bx[m*1024 + 512 + c] - 2.0f;
    rx[i] = __float2bfloat16(sigmoidf_(rpre) * x[i]);
    z[i]  = sigmoidf_(zpre);
}

__global__ __launch_bounds__(256) void gru_final_kernel(const float* __restrict__ A1,
    const float* __restrict__ C2, const float* __restrict__ z,
    const float* __restrict__ x, float* __restrict__ out)
{
    size_t i = (size_t)blockIdx.x * 256 + threadIdx.x;
    size_t m = i >> 9;
    int c = (int)(i & 511);
    float hh = tanhf(A1[m*1536 + 1024 + c] + C2[i]);
    float zz = z[i];
    out[i] = (1.0f - zz) * x[i] + zz * hh;
}

// GRU1 final fused with LN2
__global__ __launch_bounds__(256) void gru_final_ln(
    const float* __restrict__ A1, const float* __restrict__ C2,
    const float* __restrict__ z, const float* __restrict__ x,
    const float* __restrict__ g, const float* __restrict__ bta,
    float* __restrict__ g1, __hip_bfloat16* __restrict__ g1b,
    __hip_bfloat16* __restrict__ fib)
{
    int row = blockIdx.x;
    int tid = threadIdx.x;
    size_t base = (size_t)row * DM;
    float2 c2v = ((const float2*)(C2 + base))[tid];
    float2 zv  = ((const float2*)(z  + base))[tid];
    float2 xv  = ((const float2*)(x  + base))[tid];
    float2 av  = ((const float2*)(A1 + (size_t)row*1536 + 1024))[tid];
    float h0 = tanhf(av.x + c2v.x);
    float h1 = tanhf(av.y + c2v.y);
    float2 v;
    v.x = (1.0f - zv.x) * xv.x + zv.x * h0;
    v.y = (1.0f - zv.y) * xv.y + zv.y * h1;
    ((float2*)(g1 + base))[tid] = v;
    g1b[base + 2*tid+0] = __float2bfloat16(v.x);
    g1b[base + 2*tid+1] = __float2bfloat16(v.y);

    float s = v.x + v.y;
    #pragma unroll
    for (int off = 32; off; off >>= 1) s += __shfl_down(s, off);
    __shared__ float red[8];
    int wid = tid >> 6, lane = tid & 63;
    if (lane == 0) red[wid] = s;
    __syncthreads();
    if (tid == 0) red[0] = (red[0] + red[1] + red[2] + red[3]) * (1.0f / DM);
    __syncthreads();
    float mean = red[0];
    float dx = v.x - mean, dy = v.y - mean;
    float sq = dx*dx + dy*dy;
    #pragma unroll
    for (int off = 32; off; off >>= 1) sq += __shfl_down(sq, off);
    if (lane == 0) red[4 + wid] = sq;
    __syncthreads();
    if (tid == 0) red[1] = rsqrtf((red[4]+red[5]+red[6]+red[7]) * (1.0f/DM) + 1e-5f);
    __syncthreads();
    float rstd = red[1];
    float2 gg = ((const float2*)g)[tid];
    float2 bb = ((const float2*)bta)[tid];
    fib[base + 2*tid+0] = __float2bfloat16(dx * rstd * gg.x + bb.x);
    fib[base + 2*tid+1] = __float2bfloat16(dy * rstd * gg.y + bb.y);
}

// ---------------- launch --------------------------------------------------
extern "C" void kernel_launch(void* const* d_in, const int* in_sizes, int n_in,
                              void* d_out, int out_size, void* d_ws, size_t ws_size,
                              hipStream_t stream)
{
    const float* inputs = (const float*)d_in[0];
    const int*   term   = (const int*)  d_in[1];
    const float* tilde_k= (const float*)d_in[2];
    const float* tilde_v= (const float*)d_in[3];
    const float* s_prev = (const float*)d_in[4];
    const float* tick   = (const float*)d_in[5];
    const float* w_proj = (const float*)d_in[6];
    const float* b_proj = (const float*)d_in[7];
    const float* w_attn = (const float*)d_in[8];
    const float* b_attn = (const float*)d_in[9];
    const float* ln1_g  = (const float*)d_in[10];
    const float* ln1_b  = (const float*)d_in[11];
    const float* ln2_g  = (const float*)d_in[12];
    const float* ln2_b  = (const float*)d_in[13];
    const float* gru1_w = (const float*)d_in[14];
    const float* gru1_u = (const float*)d_in[15];
    const float* gru2_w = (const float*)d_in[16];
    const float* gru2_u = (const float*)d_in[17];
    const float* ffc_w1 = (const float*)d_in[18];
    const float* ffc_b1 = (const float*)d_in[19];
    const float* ffc_w2 = (const float*)d_in[20];
    const float* ffc_b2 = (const float*)d_in[21];
    float* out = (float*)d_out;
    float* ws  = (float*)d_ws;

    // ---- f32 region (floats) ----
    float* proj = ws;                       // 4096x2656 (dead after scan)
    float* A1   = ws;                       // 4096x1536 (overlays proj; written AFTER scan)
    float* C2   = ws + 10878976;            // 4096x512
    float* zb   = ws + 12976128;            // 4096x512
    float* g1   = ws + 15073280;            // 4096x512
    // ---- bf16 region ----
    __hip_bfloat16* bb = (__hip_bfloat16*)(ws + 17170432);
    __hip_bfloat16* wp_bf  = bb + 0;          // 2656x512
    __hip_bfloat16* wat_bf = bb + 1359872;    // 512x512
    __hip_bfloat16* g1w_bf = bb + 1622016;    // 3x512x512
    __hip_bfloat16* g1u_bf = bb + 2408448;
    __hip_bfloat16* g2w_bf = bb + 3194880;
    __hip_bfloat16* g2u_bf = bb + 3981312;
    __hip_bfloat16* fw1_bf = bb + 4767744;    // 2048x512
    __hip_bfloat16* fw2_bf = bb + 5816320;    // 512x2048
    __hip_bfloat16* in_bf  = bb + 6864896;    // 4096x512
    __hip_bfloat16* xn_bf  = bb + 8962048;
    __hip_bfloat16* at_bf  = bb + 11059200;
    __hip_bfloat16* y1_bf  = bb + 13156352;
    __hip_bfloat16* rx_bf  = bb + 15253504;
    __hip_bfloat16* fi_bf  = bb + 17350656;
    __hip_bfloat16* mid_bf = bb + 19447808;   // 4096x2048
    __hip_bfloat16* fo_bf  = bb + 27836416;
    __hip_bfloat16* g1_bf  = bb + 29933568;
    // Bx after bf16 region — never overlaps proj (r6 lesson).
    float* Bx = ws + 33185792;   // 4096x1024 -> total ~149.5 MB

    dim3 blk(256);

    // 1. merged f32->bf16 conversions + LN1 (one launch)
    F2B9 fa;
    const float* srcs[9] = {w_proj, w_attn, gru1_w, gru1_u, gru2_w, gru2_u,
                            ffc_w1, ffc_w2, inputs};
    __hip_bfloat16* dsts[9] = {wp_bf, wat_bf, g1w_bf, g1u_bf, g2w_bf, g2u_bf,
                               fw1_bf, fw2_bf, in_bf};
    int quads[9] = {339968, 65536, 196608, 196608, 196608, 196608,
                    262144, 262144, 524288};
    int cum = 0;
    for (int i = 0; i < 9; ++i) { fa.s[i] = srcs[i]; fa.d[i] = dsts[i]; fa.cum[i] = cum; cum += quads[i]; }
    fa.cum[9] = cum;
    f2b_ln_all<<<8752 + MM, blk, 0, stream>>>(fa, inputs, ln1_g, ln1_b, xn_bf);

    // 2. projection
    gemm_bf16<<<dim3(21, 32), blk, 0, stream>>>(xn_bf, wp_bf, b_proj, proj, nullptr, NPROJ, DM, 0);

    // 3. fused scans + attention (3-stage wave pipeline) + GRU1's Bx GEMM
    size_t dyn = (size_t)(NSLOT*SLOTF + RSLOT*RSLOTF + 64) * 4;
    scan_attn_fused<<<512, blk, dyn, stream>>>(proj, term, tick, tilde_k, tilde_v,
                                               s_prev, at_bf, in_bf, g1u_bf, Bx);

    // 4. attn out-proj (+relu)
    gemm_bf16_64<<<dim3(4, 64), blk, 0, stream>>>(at_bf, wat_bf, b_attn, nullptr, y1_bf, DM, DM, 1);

    // 5. GRU1
    gemm_bf16<<<dim3(12, 32), blk, 0, stream>>>(y1_bf, g1w_bf, nullptr, A1, nullptr, 3*DM, DM, 0);
    gru_rz_kernel<<<MM*DM/256, blk, 0, stream>>>(A1, Bx, inputs, rx_bf, zb);
    gemm_bf16_64<<<dim3(4, 64), blk, 0, stream>>>(rx_bf, g1u_bf + 2*DM*DM, nullptr, C2, nullptr, DM, DM, 0);
    gru_final_ln<<<MM, blk, 0, stream>>>(A1, C2, zb, inputs, ln2_g, ln2_b, g1, g1_bf, fi_bf);

    // 6. FFC1 + GRU2's Bx GEMM (one launch)
    ffc1_bx_dual<<<dim3(24, 32), blk, 0, stream>>>(fi_bf, fw1_bf, ffc_b1, mid_bf,
                                                   2048, 16,
                                                   g1_bf, g2u_bf, Bx, 1024, DM);

    // 7. FFC2 (+relu)
    gemm_bf16_64<<<dim3(4, 64), blk, 0, stream>>>(mid_bf, fw2_bf, ffc_b2, nullptr, fo_bf, DM, 2048, 1);

    // 8. GRU2
    gemm_bf16<<<dim3(12, 32), blk, 0, stream>>>(fo_bf, g2w_bf, nullptr, A1, nullptr, 3*DM, DM, 0);
    gru_rz_kernel<<<MM*DM/256, blk, 0, stream>>>(A1, Bx, g1, rx_bf, zb);
    gemm_bf16_64<<<dim3(4, 64), blk, 0, stream>>>(rx_bf, g2u_bf + 2*DM*DM, nullptr, C2, nullptr, DM, DM, 0);
    gru_final_kernel<<<MM*DM/256, blk, 0, stream>>>(A1, C2, zb, g1, out);
}